// Round 1
// baseline (4008.647 us; speedup 1.0000x reference)
//
#include <hip/hip_runtime.h>
#include <hip/hip_bf16.h>
#include <stdint.h>

// SymmetricHyperRBM: K=10 Gibbs chain + free-energy gap, MI355X gfx950.
// State carried as s = v_branch (double-flip identity); v = u?s:1-s only in
// reductions. All big matmuls are bf16 MFMA 16x16x32, 128x128 tiles.

#define NB 16384
#define NV 1024
#define NH 1024
#define KSTEPS 10

typedef __attribute__((ext_vector_type(8))) short bf16x8;   // 8 bf16 (4 VGPRs)
typedef __attribute__((ext_vector_type(4))) float f32x4;

__device__ __forceinline__ float rng_u01(unsigned salt, unsigned idx) {
  unsigned long long z = (((unsigned long long)salt) << 32) | (unsigned long long)idx;
  z ^= z >> 33; z *= 0xff51afd7ed558ccdULL;   // murmur3 fmix64
  z ^= z >> 33; z *= 0xc4ceb9fe1a85ec53ULL;
  z ^= z >> 33;
  return (float)((unsigned)(z >> 40)) * (1.0f / 16777216.0f);
}

__device__ __forceinline__ float sigm(float z) { return 1.0f / (1.0f + __expf(-z)); }
__device__ __forceinline__ float softplus_(float z) {
  return z > 0.f ? z + log1pf(__expf(-z)) : log1pf(__expf(z));
}
__device__ __forceinline__ float lse2(float a, float b) {
  float m = fmaxf(a, b);
  return m + log1pf(__expf(fminf(a, b) - m));
}
__device__ __forceinline__ unsigned short f2bf(float f) {
  __hip_bfloat16 h = __float2bfloat16(f);
  return *reinterpret_cast<unsigned short*>(&h);
}

// ---------------------------------------------------------------------------
// GEMM C[16384 x 1024] = A[16384 x 1024] * Bt[1024 x 1024]^T  (bf16 MFMA)
// EPI 0: h = bernoulli(sigmoid(acc + c_mod))                   -> outh
// EPI 1: dE partials (sum a, sum v*a, sum v*b_mod) + s = bernoulli(sigmoid(a+b_mod))
// EPI 2: free-energy softplus row sums (u-swap for the model pass)
// ---------------------------------------------------------------------------
template <int EPI>
__global__ __launch_bounds__(256) void gemm_bt(
    const unsigned short* __restrict__ A, const unsigned short* __restrict__ Bt,
    unsigned short* __restrict__ sh,     // EPI0: h out; EPI1: s in/out
    const float* __restrict__ mod,       // EPI0/2: c_mod; EPI1: b_mod
    const float* __restrict__ u, const float* __restrict__ wcs,
    float* __restrict__ p0, float* __restrict__ p1, float* __restrict__ p2,
    unsigned salt) {
  __shared__ __align__(16) unsigned short As[128 * 32];
  __shared__ __align__(16) unsigned short Bs[128 * 32];
  const int t = threadIdx.x;
  const int m0 = blockIdx.x * 128, n0 = blockIdx.y * 128;
  const int lane = t & 63, wave = t >> 6;
  const int wm = (wave >> 1) * 64, wn = (wave & 1) * 64;
  const int lr = lane & 15, quad = lane >> 4;

  f32x4 acc[4][4] = {};

  for (int k0 = 0; k0 < 1024; k0 += 32) {
#pragma unroll
    for (int c = 0; c < 4; ++c) {
      const int o = (c * 256 + t) * 16;
      if (o < 8192) {
        const int row = o >> 6, colb = o & 63;
        *(uint4*)((char*)As + o) =
            *(const uint4*)((const char*)(A + (size_t)(m0 + row) * 1024 + k0) + colb);
      } else {
        const int o2 = o - 8192;
        const int row = o2 >> 6, colb = o2 & 63;
        *(uint4*)((char*)Bs + o2) =
            *(const uint4*)((const char*)(Bt + (size_t)(n0 + row) * 1024 + k0) + colb);
      }
    }
    __syncthreads();
    bf16x8 af[4], bfr[4];
#pragma unroll
    for (int i = 0; i < 4; i++) af[i] = *(const bf16x8*)(As + (wm + i * 16 + lr) * 32 + quad * 8);
#pragma unroll
    for (int j = 0; j < 4; j++) bfr[j] = *(const bf16x8*)(Bs + (wn + j * 16 + lr) * 32 + quad * 8);
#pragma unroll
    for (int i = 0; i < 4; i++)
#pragma unroll
      for (int j = 0; j < 4; j++)
        acc[i][j] = __builtin_amdgcn_mfma_f32_16x16x32_bf16(af[i], bfr[j], acc[i][j], 0, 0, 0);
    __syncthreads();
  }

  // C/D layout (m89-verified): col = lane&15, row = quad*4 + reg
  if constexpr (EPI == 0) {
#pragma unroll
    for (int i = 0; i < 4; i++)
#pragma unroll
      for (int j = 0; j < 4; j++)
#pragma unroll
        for (int rg = 0; rg < 4; rg++) {
          const int r = m0 + wm + i * 16 + quad * 4 + rg;
          const int n = n0 + wn + j * 16 + lr;
          const unsigned idx = (unsigned)r * 1024u + (unsigned)n;
          const float z = acc[i][j][rg] + mod[idx];
          sh[idx] = (rng_u01(salt, idx) < sigm(z)) ? (unsigned short)0x3F80 : (unsigned short)0;
        }
  } else if constexpr (EPI == 1) {
#pragma unroll
    for (int i = 0; i < 4; i++)
#pragma unroll
      for (int rg = 0; rg < 4; rg++) {
        const int r = m0 + wm + i * 16 + quad * 4 + rg;
        const float uu = u[r];
        float pa = 0.f, pva = 0.f, pvb = 0.f;
#pragma unroll
        for (int j = 0; j < 4; j++) {
          const int n = n0 + wn + j * 16 + lr;
          const unsigned idx = (unsigned)r * 1024u + (unsigned)n;
          const float a = acc[i][j][rg];
          const float bm = mod[idx];
          const float so = (sh[idx] != 0) ? 1.f : 0.f;
          const float v = (uu != 0.f) ? so : 1.f - so;  // v_t = u?s:1-s
          pa += a; pva += v * a; pvb += v * bm;
          sh[idx] = (rng_u01(salt, idx) < sigm(a + bm)) ? (unsigned short)0x3F80
                                                        : (unsigned short)0;
        }
#pragma unroll
        for (int msk = 1; msk < 16; msk <<= 1) {  // reduce across the 16 lanes of the quad
          pa += __shfl_xor(pa, msk, 64);
          pva += __shfl_xor(pva, msk, 64);
          pvb += __shfl_xor(pvb, msk, 64);
        }
        if (lr == 0) {
          atomicAdd(&p0[r], pa);
          atomicAdd(&p1[r], pva);
          atomicAdd(&p2[r], pvb);
        }
      }
  } else {
#pragma unroll
    for (int i = 0; i < 4; i++)
#pragma unroll
      for (int rg = 0; rg < 4; rg++) {
        const int r = m0 + wm + i * 16 + quad * 4 + rg;
        const bool uu = (u == nullptr) ? true : (u[r] != 0.f);
        float sn = 0.f, sf = 0.f;
#pragma unroll
        for (int j = 0; j < 4; j++) {
          const int n = n0 + wn + j * 16 + lr;
          const unsigned idx = (unsigned)r * 1024u + (unsigned)n;
          const float vw = acc[i][j][rg];
          const float cm = mod[idx];
          const float s1 = softplus_(vw + cm);            // softplus(vW + c_mod)
          const float s2 = softplus_(wcs[n] - vw + cm);   // softplus(Wcs - vW + c_mod)
          sn += uu ? s1 : s2;  // u=0 flips v -> vW := Wcs - vW, swapping branches
          sf += uu ? s2 : s1;
        }
#pragma unroll
        for (int msk = 1; msk < 16; msk <<= 1) {
          sn += __shfl_xor(sn, msk, 64);
          sf += __shfl_xor(sf, msk, 64);
        }
        if (lr == 0) { atomicAdd(&p0[r], sn); atomicAdd(&p1[r], sf); }
      }
  }
}

// ------------------------- setup / small kernels ---------------------------
__global__ __launch_bounds__(256) void k_prep_w(const float* __restrict__ W,
                                                unsigned short* __restrict__ Wbf,
                                                unsigned short* __restrict__ Wt) {
  int idx = blockIdx.x * 256 + threadIdx.x;
  int i = idx >> 10, j = idx & 1023;
  unsigned short v = f2bf(W[idx]);
  Wbf[idx] = v;
  Wt[(size_t)j * 1024 + i] = v;
}

__global__ __launch_bounds__(256) void k_wcs(const float* __restrict__ W, float* __restrict__ wcs) {
  int n = blockIdx.x * 256 + threadIdx.x;
  float s = 0.f;
  for (int i = 0; i < 1024; i++) s += W[(size_t)i * 1024 + n];
  wcs[n] = s;
}

__global__ __launch_bounds__(256) void k_x(const float* __restrict__ cond,
                                           const float* __restrict__ fc1w,
                                           const float* __restrict__ fc1b, float* __restrict__ X) {
  int idx = blockIdx.x * 256 + threadIdx.x;  // NB*64
  int r = idx >> 6, k = idx & 63;
  X[idx] = tanhf(cond[r] * fc1w[k] + fc1b[k]);
}

// Fold FiLM into rank-64 form: b_mod[r][j] = cstb[j] + X[r]·Gb[j]
__global__ __launch_bounds__(256) void k_g(const float* __restrict__ fc2w,
                                           const float* __restrict__ fc2b,
                                           const float* __restrict__ b, const float* __restrict__ c,
                                           float* __restrict__ Gb, float* __restrict__ Gc,
                                           float* __restrict__ cstb, float* __restrict__ cstc) {
  int idx = blockIdx.x * 256 + threadIdx.x;  // 1024*64
  int j = idx >> 6, k = idx & 63;
  Gb[idx] = fc2w[(size_t)j * 64 + k] * b[j] + fc2w[(size_t)(1024 + j) * 64 + k];
  Gc[idx] = fc2w[(size_t)(2048 + j) * 64 + k] * c[j] + fc2w[(size_t)(3072 + j) * 64 + k];
  if (k == 0) {
    cstb[j] = b[j] + fc2b[j] * b[j] + fc2b[1024 + j];
    cstc[j] = c[j] + fc2b[2048 + j] * c[j] + fc2b[3072 + j];
  }
}

// out[128rows x 128cols] = X[rows x 64] @ G[cols x 64]^T + cst  (fp32)
__global__ __launch_bounds__(256) void k_bmod(const float* __restrict__ X,
                                              const float* __restrict__ G,
                                              const float* __restrict__ cst,
                                              float* __restrict__ out) {
  __shared__ __align__(16) float Xs[128 * 64];
  __shared__ __align__(16) float Gs[128 * 64];
  const int t = threadIdx.x;
  const int r0 = blockIdx.x * 128, c0 = blockIdx.y * 128;
#pragma unroll
  for (int c = 0; c < 8; ++c) {
    int i4 = c * 256 + t;
    ((float4*)Xs)[i4] = ((const float4*)(X + (size_t)r0 * 64))[i4];
    ((float4*)Gs)[i4] = ((const float4*)(G + (size_t)c0 * 64))[i4];
  }
  __syncthreads();
  const int tr = (t >> 4) * 8, tc = (t & 15) * 8;
  float acc[8][8] = {};
  for (int k = 0; k < 64; k += 4) {
    float4 xa[8], gb[8];
#pragma unroll
    for (int i = 0; i < 8; i++) xa[i] = *(const float4*)(Xs + (tr + i) * 64 + k);
#pragma unroll
    for (int j = 0; j < 8; j++) gb[j] = *(const float4*)(Gs + (tc + j) * 64 + k);
#pragma unroll
    for (int i = 0; i < 8; i++)
#pragma unroll
      for (int j = 0; j < 8; j++)
        acc[i][j] += xa[i].x * gb[j].x + xa[i].y * gb[j].y + xa[i].z * gb[j].z + xa[i].w * gb[j].w;
  }
#pragma unroll
  for (int i = 0; i < 8; i++)
#pragma unroll
    for (int j = 0; j < 8; j++)
      out[(size_t)(r0 + tr + i) * 1024 + (c0 + tc + j)] = acc[i][j] + cst[c0 + tc + j];
}

__global__ __launch_bounds__(256) void k_u0(float* __restrict__ u) {
  int r = blockIdx.x * 256 + threadIdx.x;
  u[r] = (rng_u01(1000u, (unsigned)r) < 0.5f) ? 1.f : 0.f;
}

__global__ __launch_bounds__(256) void k_sinit(const float* __restrict__ vdata,
                                               const float* __restrict__ u,
                                               unsigned short* __restrict__ s,
                                               unsigned short* __restrict__ vbf) {
  int idx = blockIdx.x * 256 + threadIdx.x;
  int r = idx >> 10;
  float vd = vdata[idx];
  vbf[idx] = (vd != 0.f) ? (unsigned short)0x3F80 : (unsigned short)0;
  float sv = (u[r] != 0.f) ? vd : 1.f - vd;  // s_0 = v_branch at step 1
  s[idx] = (sv != 0.f) ? (unsigned short)0x3F80 : (unsigned short)0;
}

__global__ __launch_bounds__(256) void k_sb(const float* __restrict__ bmod, float* __restrict__ sb) {
  __shared__ float red[4];
  int r = blockIdx.x, t = threadIdx.x;
  const float* row = bmod + (size_t)r * 1024;
  float s = 0.f;
  for (int j = t; j < 1024; j += 256) s += row[j];
  for (int m = 32; m >= 1; m >>= 1) s += __shfl_xor(s, m, 64);
  if ((t & 63) == 0) red[t >> 6] = s;
  __syncthreads();
  if (t == 0) sb[r] = red[0] + red[1] + red[2] + red[3];
}

__global__ __launch_bounds__(256) void k_ustep(float* __restrict__ u, const float* __restrict__ sb,
                                               float* __restrict__ pa, float* __restrict__ pva,
                                               float* __restrict__ pvb, unsigned salt) {
  int r = blockIdx.x * 256 + threadIdx.x;
  float dE = -sb[r] - pa[r] + 2.f * pvb[r] + 2.f * pva[r];
  u[r] = (rng_u01(salt, (unsigned)r) < sigm(dE)) ? 1.f : 0.f;
  pa[r] = 0.f; pva[r] = 0.f; pvb[r] = 0.f;  // re-zero for next step
}

__global__ __launch_bounds__(256) void k_final(
    const float* __restrict__ vdata, const unsigned short* __restrict__ s,
    const float* __restrict__ bmod, const float* __restrict__ u, const float* __restrict__ sb,
    const float* __restrict__ spn_d, const float* __restrict__ spf_d,
    const float* __restrict__ spn_m, const float* __restrict__ spf_m, float* __restrict__ fdiff) {
  __shared__ float red1[4], red2[4];
  int r = blockIdx.x, t = threadIdx.x;
  const float* brow = bmod + (size_t)r * 1024;
  const float* vrow = vdata + (size_t)r * 1024;
  const unsigned short* srow = s + (size_t)r * 1024;
  float d1 = 0.f, d2 = 0.f;
  for (int j = t; j < 1024; j += 256) {
    float bm = brow[j];
    d1 += vrow[j] * bm;
    d2 += (srow[j] != 0) ? bm : 0.f;
  }
  for (int m = 32; m >= 1; m >>= 1) {
    d1 += __shfl_xor(d1, m, 64);
    d2 += __shfl_xor(d2, m, 64);
  }
  if ((t & 63) == 0) { red1[t >> 6] = d1; red2[t >> 6] = d2; }
  __syncthreads();
  if (t == 0) {
    d1 = red1[0] + red1[1] + red1[2] + red1[3];
    d2 = red2[0] + red2[1] + red2[2] + red2[3];
    float sbv = sb[r];
    float Fn_d = -d1 - spn_d[r];
    float Ff_d = -(sbv - d1) - spf_d[r];
    float F_d = -lse2(-Fn_d, -Ff_d);
    float vbn = (u[r] != 0.f) ? d2 : (sbv - d2);  // sum(v_model * b_mod)
    float Fn_m = -vbn - spn_m[r];
    float Ff_m = -(sbv - vbn) - spf_m[r];
    float F_m = -lse2(-Fn_m, -Ff_m);
    fdiff[r] = F_d - F_m;
  }
}

__global__ __launch_bounds__(256) void k_reduce(const float* __restrict__ fdiff,
                                                float* __restrict__ out) {
  __shared__ float red[4];
  int t = threadIdx.x;
  float s = 0.f;
  for (int i = t; i < NB; i += 256) s += fdiff[i];
  for (int m = 32; m >= 1; m >>= 1) s += __shfl_xor(s, m, 64);
  if ((t & 63) == 0) red[t >> 6] = s;
  __syncthreads();
  if (t == 0) out[0] = (red[0] + red[1] + red[2] + red[3]) * (1.0f / (float)NB);
}

// ---------------------------------------------------------------------------
extern "C" void kernel_launch(void* const* d_in, const int* in_sizes, int n_in, void* d_out,
                              int out_size, void* d_ws, size_t ws_size, hipStream_t stream) {
  const float* vdata = (const float*)d_in[0];
  const float* cond = (const float*)d_in[1];
  const float* W = (const float*)d_in[2];
  const float* bb = (const float*)d_in[3];
  const float* cc = (const float*)d_in[4];
  const float* fc1w = (const float*)d_in[5];
  const float* fc1b = (const float*)d_in[6];
  const float* fc2w = (const float*)d_in[7];
  const float* fc2b = (const float*)d_in[8];
  float* out = (float*)d_out;

  char* wp = (char*)d_ws;
  auto alloc = [&](size_t bytes) {
    char* p = wp;
    wp += (bytes + 255) & ~(size_t)255;
    return p;
  };
  unsigned short* Wbf = (unsigned short*)alloc((size_t)1024 * 1024 * 2);
  unsigned short* Wt = (unsigned short*)alloc((size_t)1024 * 1024 * 2);
  float* wcs = (float*)alloc(1024 * 4);
  float* X = (float*)alloc((size_t)NB * 64 * 4);
  float* Gb = (float*)alloc((size_t)1024 * 64 * 4);
  float* Gc = (float*)alloc((size_t)1024 * 64 * 4);
  float* cstb = (float*)alloc(1024 * 4);
  float* cstc = (float*)alloc(1024 * 4);
  float* bmod = (float*)alloc((size_t)NB * 1024 * 4);
  float* cmod = (float*)alloc((size_t)NB * 1024 * 4);
  float* sb = (float*)alloc(NB * 4);
  float* u = (float*)alloc(NB * 4);
  unsigned short* s = (unsigned short*)alloc((size_t)NB * 1024 * 2);
  unsigned short* h = (unsigned short*)alloc((size_t)NB * 1024 * 2);
  unsigned short* vbf = (unsigned short*)alloc((size_t)NB * 1024 * 2);
  float* pa = (float*)alloc(NB * 4);  // 8 contiguous 64KB arrays below; single memset
  float* pva = (float*)alloc(NB * 4);
  float* pvb = (float*)alloc(NB * 4);
  float* spn_d = (float*)alloc(NB * 4);
  float* spf_d = (float*)alloc(NB * 4);
  float* spn_m = (float*)alloc(NB * 4);
  float* spf_m = (float*)alloc(NB * 4);
  float* fdiff = (float*)alloc(NB * 4);

  hipMemsetAsync(pa, 0, (size_t)NB * 4 * 7, stream);

  k_prep_w<<<4096, 256, 0, stream>>>(W, Wbf, Wt);
  k_wcs<<<4, 256, 0, stream>>>(W, wcs);
  k_x<<<4096, 256, 0, stream>>>(cond, fc1w, fc1b, X);
  k_g<<<256, 256, 0, stream>>>(fc2w, fc2b, bb, cc, Gb, Gc, cstb, cstc);
  dim3 bgrid(NB / 128, 1024 / 128);
  k_bmod<<<bgrid, 256, 0, stream>>>(X, Gb, cstb, bmod);
  k_bmod<<<bgrid, 256, 0, stream>>>(X, Gc, cstc, cmod);
  k_u0<<<NB / 256, 256, 0, stream>>>(u);
  k_sinit<<<NB * 1024 / 256, 256, 0, stream>>>(vdata, u, s, vbf);
  k_sb<<<NB, 256, 0, stream>>>(bmod, sb);

  dim3 ggrid(NB / 128, 1024 / 128);
  for (int step = 0; step < KSTEPS; ++step) {
    // h ~ Bern(sigmoid(s@W + c_mod))
    gemm_bt<0><<<ggrid, 256, 0, stream>>>(s, Wt, h, cmod, nullptr, nullptr, nullptr, nullptr,
                                          nullptr, 2000u + (unsigned)step);
    // a = h@W^T; dE partials; s_new ~ Bern(sigmoid(a + b_mod))
    gemm_bt<1><<<ggrid, 256, 0, stream>>>(h, Wbf, s, bmod, u, nullptr, pa, pva, pvb,
                                          3000u + (unsigned)step);
    // u_new ~ Bern(sigmoid(dE)); zero partials
    k_ustep<<<NB / 256, 256, 0, stream>>>(u, sb, pa, pva, pvb, 4000u + (unsigned)step);
  }

  // Free energy softplus sums: data pass (u=1 identically) and model pass (u-swapped)
  gemm_bt<2><<<ggrid, 256, 0, stream>>>(vbf, Wt, nullptr, cmod, nullptr, wcs, spn_d, spf_d,
                                        nullptr, 0u);
  gemm_bt<2><<<ggrid, 256, 0, stream>>>(s, Wt, nullptr, cmod, u, wcs, spn_m, spf_m, nullptr, 0u);
  k_final<<<NB, 256, 0, stream>>>(vdata, s, bmod, u, sb, spn_d, spf_d, spn_m, spf_m, fdiff);
  k_reduce<<<1, 256, 0, stream>>>(fdiff, out);
}

// Round 2
// 3756.896 us; speedup vs baseline: 1.0670x; 1.0670x over previous
//
#include <hip/hip_runtime.h>
#include <hip/hip_bf16.h>
#include <stdint.h>

// SymmetricHyperRBM on MI355X. K=10 Gibbs chain + free-energy gap.
// Rank-64 FiLM biases folded into GEMM K-dim: A'=[state|X|1|pad] (K=1120),
// B'=[W|G|cst|pad], so accumulators ARE the logits (no bias reads).
// dE = -sum(z) + 2*sum(v*z) with z = a + b_mod (pairwise identity).

#define NB 16384
#define NV 1024
#define NH 1024
#define KSTEPS 10
#define LDA 1120  // 1024 + 64 (X) + 1 (const) + 31 (pad); 35 K-iters of 32

typedef __attribute__((ext_vector_type(8))) short bf16x8;
typedef __attribute__((ext_vector_type(4))) float f32x4;

__device__ __forceinline__ float rng_u01(unsigned salt, unsigned idx) {
  unsigned x = idx + salt * 0x9E3779B9u;          // lowbias32 hash
  x = (x ^ (x >> 16)) * 0x7feb352du;
  x = (x ^ (x >> 15)) * 0x846ca68bu;
  x = x ^ (x >> 16);
  return (float)(x >> 8) * (1.0f / 16777216.0f);
}
__device__ __forceinline__ float sigm(float z) { return 1.0f / (1.0f + __expf(-z)); }
__device__ __forceinline__ float softplus_(float z) {
  return z > 0.f ? z + log1pf(__expf(-z)) : log1pf(__expf(z));
}
__device__ __forceinline__ float lse2(float a, float b) {
  float m = fmaxf(a, b);
  return m + log1pf(__expf(fminf(a, b) - m));
}
__device__ __forceinline__ unsigned short f2bf(float f) {
  __hip_bfloat16 h = __float2bfloat16(f);
  return *reinterpret_cast<unsigned short*>(&h);
}
__device__ __forceinline__ void gl2lds16(const void* g, void* l) {
  __builtin_amdgcn_global_load_lds(
      (const __attribute__((address_space(1))) unsigned int*)g,
      (__attribute__((address_space(3))) unsigned int*)l, 16, 0, 0);
}

// ---------------------------------------------------------------------------
// C[16384 x 1024] = A[16384 x LDA(used Kdim)] * Bt[1024 x LDA]^T, bf16 MFMA,
// 128x128 tile, global_load_lds width-16 staging (m97 structure).
// EPI 0: h = bern(sigm(z)) -> H                    (z = sW + c_mod via ext-K)
// EPI 1: p0+=sum z, p1+=sum v*z (v=u?s_old:1-s_old); s_new = bern(sigm(z))
// EPI 2: free-energy softplus row sums (reads cmod; u-swap for model pass)
// ---------------------------------------------------------------------------
template <int EPI>
__global__ __launch_bounds__(256) void gemm_bt(
    const unsigned short* __restrict__ A, const unsigned short* __restrict__ Bt,
    unsigned short* __restrict__ sh,   // EPI0: H out; EPI1: S in/out
    const float* __restrict__ mod,     // EPI2: cmod
    const float* __restrict__ u, const float* __restrict__ wcs,
    float* __restrict__ p0, float* __restrict__ p1, unsigned salt, int Kdim) {
  __shared__ __align__(16) unsigned short As[128 * 32];
  __shared__ __align__(16) unsigned short Bs[128 * 32];
  const int t = threadIdx.x;
  const int m0 = blockIdx.x * 128, n0 = blockIdx.y * 128;
  const int lane = t & 63, wave = t >> 6;
  const int wm = (wave >> 1) * 64, wn = (wave & 1) * 64;
  const int lr = lane & 15, quad = lane >> 4;
  const int srow = lane >> 2;          // 0..15 within a wave's 16-row chunk
  const int scol = (lane & 3) * 16;    // byte offset within 64B k-slice

  f32x4 acc[4][4] = {};

  for (int k0 = 0; k0 < Kdim; k0 += 32) {
#pragma unroll
    for (int c = 0; c < 2; ++c) {
      const int row = c * 64 + wave * 16 + srow;
      gl2lds16((const char*)(A + (size_t)(m0 + row) * LDA + k0) + scol,
               (char*)As + c * 4096 + wave * 1024);
      gl2lds16((const char*)(Bt + (size_t)(n0 + row) * LDA + k0) + scol,
               (char*)Bs + c * 4096 + wave * 1024);
    }
    __syncthreads();
    bf16x8 af[4], bfr[4];
#pragma unroll
    for (int i = 0; i < 4; i++) af[i] = *(const bf16x8*)(As + (wm + i * 16 + lr) * 32 + quad * 8);
#pragma unroll
    for (int j = 0; j < 4; j++) bfr[j] = *(const bf16x8*)(Bs + (wn + j * 16 + lr) * 32 + quad * 8);
#pragma unroll
    for (int i = 0; i < 4; i++)
#pragma unroll
      for (int j = 0; j < 4; j++)
        acc[i][j] = __builtin_amdgcn_mfma_f32_16x16x32_bf16(af[i], bfr[j], acc[i][j], 0, 0, 0);
    __syncthreads();
  }

  // C/D layout (m89-verified): col = lane&15, row = quad*4 + reg
  if constexpr (EPI == 0) {
#pragma unroll
    for (int i = 0; i < 4; i++)
#pragma unroll
      for (int j = 0; j < 4; j++)
#pragma unroll
        for (int rg = 0; rg < 4; rg++) {
          const int r = m0 + wm + i * 16 + quad * 4 + rg;
          const int n = n0 + wn + j * 16 + lr;
          const float z = acc[i][j][rg];
          sh[(size_t)r * LDA + n] = (rng_u01(salt, (unsigned)(r << 10) + n) < sigm(z))
                                        ? (unsigned short)0x3F80 : (unsigned short)0;
        }
  } else if constexpr (EPI == 1) {
#pragma unroll
    for (int i = 0; i < 4; i++)
#pragma unroll
      for (int rg = 0; rg < 4; rg++) {
        const int r = m0 + wm + i * 16 + quad * 4 + rg;
        const float uu = u[r];
        float q0 = 0.f, q1 = 0.f;
#pragma unroll
        for (int j = 0; j < 4; j++) {
          const int n = n0 + wn + j * 16 + lr;
          const size_t idx = (size_t)r * LDA + n;
          const float z = acc[i][j][rg];
          const float so = (sh[idx] != 0) ? 1.f : 0.f;
          const float v = (uu != 0.f) ? so : 1.f - so;  // v_t = u ? s : 1-s
          q0 += z; q1 += v * z;
          sh[idx] = (rng_u01(salt, (unsigned)(r << 10) + n) < sigm(z))
                        ? (unsigned short)0x3F80 : (unsigned short)0;
        }
#pragma unroll
        for (int msk = 1; msk < 16; msk <<= 1) {
          q0 += __shfl_xor(q0, msk, 64);
          q1 += __shfl_xor(q1, msk, 64);
        }
        if (lr == 0) { atomicAdd(&p0[r], q0); atomicAdd(&p1[r], q1); }
      }
  } else {
#pragma unroll
    for (int i = 0; i < 4; i++)
#pragma unroll
      for (int rg = 0; rg < 4; rg++) {
        const int r = m0 + wm + i * 16 + quad * 4 + rg;
        const bool uu = (u == nullptr) ? true : (u[r] != 0.f);
        float sn = 0.f, sf = 0.f;
#pragma unroll
        for (int j = 0; j < 4; j++) {
          const int n = n0 + wn + j * 16 + lr;
          const float vw = acc[i][j][rg];
          const float cm = mod[(size_t)r * 1024 + n];
          const float s1 = softplus_(vw + cm);
          const float s2 = softplus_(wcs[n] - vw + cm);
          sn += uu ? s1 : s2;
          sf += uu ? s2 : s1;
        }
#pragma unroll
        for (int msk = 1; msk < 16; msk <<= 1) {
          sn += __shfl_xor(sn, msk, 64);
          sf += __shfl_xor(sf, msk, 64);
        }
        if (lr == 0) { atomicAdd(&p0[r], sn); atomicAdd(&p1[r], sf); }
      }
  }
}

// ------------------------- setup / small kernels ---------------------------
__global__ __launch_bounds__(256) void k_x(const float* __restrict__ cond,
                                           const float* __restrict__ fc1w,
                                           const float* __restrict__ fc1b, float* __restrict__ X) {
  int idx = blockIdx.x * 256 + threadIdx.x;  // NB*64
  int r = idx >> 6, k = idx & 63;
  X[idx] = tanhf(cond[r] * fc1w[k] + fc1b[k]);
}

__global__ __launch_bounds__(256) void k_g(const float* __restrict__ fc2w,
                                           const float* __restrict__ fc2b,
                                           const float* __restrict__ b, const float* __restrict__ c,
                                           float* __restrict__ Gb, float* __restrict__ Gc,
                                           float* __restrict__ cstb, float* __restrict__ cstc) {
  int idx = blockIdx.x * 256 + threadIdx.x;  // 1024*64
  int j = idx >> 6, k = idx & 63;
  Gb[idx] = fc2w[(size_t)j * 64 + k] * b[j] + fc2w[(size_t)(1024 + j) * 64 + k];
  Gc[idx] = fc2w[(size_t)(2048 + j) * 64 + k] * c[j] + fc2w[(size_t)(3072 + j) * 64 + k];
  if (k == 0) {
    cstb[j] = b[j] + fc2b[j] * b[j] + fc2b[1024 + j];
    cstc[j] = c[j] + fc2b[2048 + j] * c[j] + fc2b[3072 + j];
  }
}

// Build extended B matrices: Wt'[n][k]=[W^T | Gc | cstc | 0], Wb'[n][k]=[W | Gb | cstb | 0]
__global__ __launch_bounds__(256) void k_prep(const float* __restrict__ W,
                                              const float* __restrict__ Gb,
                                              const float* __restrict__ Gc,
                                              const float* __restrict__ cstb,
                                              const float* __restrict__ cstc,
                                              unsigned short* __restrict__ Wt,
                                              unsigned short* __restrict__ Wb) {
  int k = blockIdx.x * 256 + threadIdx.x;
  int n = blockIdx.y;
  if (k >= LDA) return;
  unsigned short wt, wb;
  if (k < 1024) {
    wt = f2bf(W[(size_t)k * 1024 + n]);
    wb = f2bf(W[(size_t)n * 1024 + k]);
  } else if (k < 1088) {
    int j = k - 1024;
    wt = f2bf(Gc[(size_t)n * 64 + j]);
    wb = f2bf(Gb[(size_t)n * 64 + j]);
  } else if (k == 1088) {
    wt = f2bf(cstc[n]);
    wb = f2bf(cstb[n]);
  } else { wt = 0; wb = 0; }
  Wt[(size_t)n * LDA + k] = wt;
  Wb[(size_t)n * LDA + k] = wb;
}

__global__ __launch_bounds__(256) void k_wcs(const float* __restrict__ W, float* __restrict__ wcs) {
  int n = blockIdx.x * 256 + threadIdx.x;
  float s = 0.f;
  for (int i = 0; i < 1024; i++) s += W[(size_t)i * 1024 + n];
  wcs[n] = s;
}

// out[128 x 128] = X[. x 64] @ G[. x 64]^T + cst (fp32) — bias materialization
__global__ __launch_bounds__(256) void k_bmod(const float* __restrict__ X,
                                              const float* __restrict__ G,
                                              const float* __restrict__ cst,
                                              float* __restrict__ out) {
  __shared__ __align__(16) float Xs[128 * 64];
  __shared__ __align__(16) float Gs[128 * 64];
  const int t = threadIdx.x;
  const int r0 = blockIdx.x * 128, c0 = blockIdx.y * 128;
#pragma unroll
  for (int c = 0; c < 8; ++c) {
    int i4 = c * 256 + t;
    ((float4*)Xs)[i4] = ((const float4*)(X + (size_t)r0 * 64))[i4];
    ((float4*)Gs)[i4] = ((const float4*)(G + (size_t)c0 * 64))[i4];
  }
  __syncthreads();
  const int tr = (t >> 4) * 8, tc = (t & 15) * 8;
  float acc[8][8] = {};
  for (int k = 0; k < 64; k += 4) {
    float4 xa[8], gb[8];
#pragma unroll
    for (int i = 0; i < 8; i++) xa[i] = *(const float4*)(Xs + (tr + i) * 64 + k);
#pragma unroll
    for (int j = 0; j < 8; j++) gb[j] = *(const float4*)(Gs + (tc + j) * 64 + k);
#pragma unroll
    for (int i = 0; i < 8; i++)
#pragma unroll
      for (int j = 0; j < 8; j++)
        acc[i][j] += xa[i].x * gb[j].x + xa[i].y * gb[j].y + xa[i].z * gb[j].z + xa[i].w * gb[j].w;
  }
#pragma unroll
  for (int i = 0; i < 8; i++)
#pragma unroll
    for (int j = 0; j < 8; j++)
      out[(size_t)(r0 + tr + i) * 1024 + (c0 + tc + j)] = acc[i][j] + cst[c0 + tc + j];
}

__global__ __launch_bounds__(256) void k_u0(float* __restrict__ u) {
  int r = blockIdx.x * 256 + threadIdx.x;
  u[r] = (rng_u01(0xABCD1234u, (unsigned)r) < 0.5f) ? 1.f : 0.f;
}

// Fill S (state+X'), H (X' cols), V (v_data cols) arrays
__global__ __launch_bounds__(256) void k_sinit(const float* __restrict__ vdata,
                                               const float* __restrict__ u,
                                               const float* __restrict__ X,
                                               unsigned short* __restrict__ S,
                                               unsigned short* __restrict__ H,
                                               unsigned short* __restrict__ V) {
  int k = blockIdx.x * 256 + threadIdx.x;
  int r = blockIdx.y;
  if (k >= LDA) return;
  const size_t o = (size_t)r * LDA + k;
  if (k < 1024) {
    float vd = vdata[(size_t)r * 1024 + k];
    V[o] = (vd != 0.f) ? (unsigned short)0x3F80 : (unsigned short)0;
    float sv = (u[r] != 0.f) ? vd : 1.f - vd;  // s_1 = v_branch at step 1
    S[o] = (sv != 0.f) ? (unsigned short)0x3F80 : (unsigned short)0;
  } else {
    unsigned short xv;
    if (k < 1088) xv = f2bf(X[(size_t)r * 64 + (k - 1024)]);
    else if (k == 1088) xv = (unsigned short)0x3F80;  // 1.0
    else xv = 0;
    S[o] = xv; H[o] = xv;
  }
}

__global__ __launch_bounds__(256) void k_ustep(float* __restrict__ u, float* __restrict__ p0,
                                               float* __restrict__ p1, unsigned salt) {
  int r = blockIdx.x * 256 + threadIdx.x;
  float dE = -p0[r] + 2.f * p1[r];
  u[r] = (rng_u01(salt, (unsigned)r) < sigm(dE)) ? 1.f : 0.f;
  p0[r] = 0.f; p1[r] = 0.f;
}

__global__ __launch_bounds__(256) void k_final(
    const float* __restrict__ vdata, const unsigned short* __restrict__ S,
    const float* __restrict__ bmod, const float* __restrict__ u,
    const float* __restrict__ spn_d, const float* __restrict__ spf_d,
    const float* __restrict__ spn_m, const float* __restrict__ spf_m, float* __restrict__ fdiff) {
  __shared__ float red0[4], red1[4], red2[4];
  int r = blockIdx.x, t = threadIdx.x;
  const float* brow = bmod + (size_t)r * 1024;
  const float* vrow = vdata + (size_t)r * 1024;
  const unsigned short* srow = S + (size_t)r * LDA;
  float d0 = 0.f, d1 = 0.f, d2 = 0.f;
  for (int j = t; j < 1024; j += 256) {
    float bm = brow[j];
    d0 += bm;
    d1 += vrow[j] * bm;
    d2 += (srow[j] != 0) ? bm : 0.f;
  }
  for (int m = 32; m >= 1; m >>= 1) {
    d0 += __shfl_xor(d0, m, 64);
    d1 += __shfl_xor(d1, m, 64);
    d2 += __shfl_xor(d2, m, 64);
  }
  if ((t & 63) == 0) { red0[t >> 6] = d0; red1[t >> 6] = d1; red2[t >> 6] = d2; }
  __syncthreads();
  if (t == 0) {
    d0 = red0[0] + red0[1] + red0[2] + red0[3];
    d1 = red1[0] + red1[1] + red1[2] + red1[3];
    d2 = red2[0] + red2[1] + red2[2] + red2[3];
    float Fn_d = -d1 - spn_d[r];
    float Ff_d = -(d0 - d1) - spf_d[r];
    float F_d = -lse2(-Fn_d, -Ff_d);
    float vbn = (u[r] != 0.f) ? d2 : (d0 - d2);  // sum(v_model * b_mod)
    float Fn_m = -vbn - spn_m[r];
    float Ff_m = -(d0 - vbn) - spf_m[r];
    float F_m = -lse2(-Fn_m, -Ff_m);
    fdiff[r] = F_d - F_m;
  }
}

__global__ __launch_bounds__(256) void k_reduce(const float* __restrict__ fdiff,
                                                float* __restrict__ out) {
  __shared__ float red[4];
  int t = threadIdx.x;
  float s = 0.f;
  for (int i = t; i < NB; i += 256) s += fdiff[i];
  for (int m = 32; m >= 1; m >>= 1) s += __shfl_xor(s, m, 64);
  if ((t & 63) == 0) red[t >> 6] = s;
  __syncthreads();
  if (t == 0) out[0] = (red[0] + red[1] + red[2] + red[3]) * (1.0f / (float)NB);
}

// ---------------------------------------------------------------------------
extern "C" void kernel_launch(void* const* d_in, const int* in_sizes, int n_in, void* d_out,
                              int out_size, void* d_ws, size_t ws_size, hipStream_t stream) {
  const float* vdata = (const float*)d_in[0];
  const float* cond = (const float*)d_in[1];
  const float* W = (const float*)d_in[2];
  const float* bb = (const float*)d_in[3];
  const float* cc = (const float*)d_in[4];
  const float* fc1w = (const float*)d_in[5];
  const float* fc1b = (const float*)d_in[6];
  const float* fc2w = (const float*)d_in[7];
  const float* fc2b = (const float*)d_in[8];
  float* out = (float*)d_out;

  char* wp = (char*)d_ws;
  auto alloc = [&](size_t bytes) {
    char* p = wp;
    wp += (bytes + 255) & ~(size_t)255;
    return p;
  };
  unsigned short* Wt = (unsigned short*)alloc((size_t)1024 * LDA * 2);
  unsigned short* Wb = (unsigned short*)alloc((size_t)1024 * LDA * 2);
  float* wcs = (float*)alloc(1024 * 4);
  float* X = (float*)alloc((size_t)NB * 64 * 4);
  float* Gb = (float*)alloc((size_t)1024 * 64 * 4);
  float* Gc = (float*)alloc((size_t)1024 * 64 * 4);
  float* cstb = (float*)alloc(1024 * 4);
  float* cstc = (float*)alloc(1024 * 4);
  float* bmod = (float*)alloc((size_t)NB * 1024 * 4);
  float* cmod = (float*)alloc((size_t)NB * 1024 * 4);
  float* u = (float*)alloc(NB * 4);
  unsigned short* S = (unsigned short*)alloc((size_t)NB * LDA * 2);
  unsigned short* H = (unsigned short*)alloc((size_t)NB * LDA * 2);
  unsigned short* V = (unsigned short*)alloc((size_t)NB * LDA * 2);
  float* p0 = (float*)alloc(NB * 4);  // contiguous: p0,p1,spn_d,spf_d,spn_m,spf_m
  float* p1 = (float*)alloc(NB * 4);
  float* spn_d = (float*)alloc(NB * 4);
  float* spf_d = (float*)alloc(NB * 4);
  float* spn_m = (float*)alloc(NB * 4);
  float* spf_m = (float*)alloc(NB * 4);
  float* fdiff = (float*)alloc(NB * 4);

  hipMemsetAsync(p0, 0, (size_t)NB * 4 * 6, stream);

  k_x<<<NB * 64 / 256, 256, 0, stream>>>(cond, fc1w, fc1b, X);
  k_g<<<1024 * 64 / 256, 256, 0, stream>>>(fc2w, fc2b, bb, cc, Gb, Gc, cstb, cstc);
  k_prep<<<dim3(5, 1024), 256, 0, stream>>>(W, Gb, Gc, cstb, cstc, Wt, Wb);
  k_wcs<<<4, 256, 0, stream>>>(W, wcs);
  dim3 bgrid(NB / 128, 1024 / 128);
  k_bmod<<<bgrid, 256, 0, stream>>>(X, Gb, cstb, bmod);
  k_bmod<<<bgrid, 256, 0, stream>>>(X, Gc, cstc, cmod);
  k_u0<<<NB / 256, 256, 0, stream>>>(u);
  k_sinit<<<dim3(5, NB), 256, 0, stream>>>(vdata, u, X, S, H, V);

  dim3 ggrid(NB / 128, 1024 / 128);
  for (int step = 0; step < KSTEPS; ++step) {
    // z1 = s@W + c_mod (ext-K); h ~ Bern(sigm(z1)) -> H
    gemm_bt<0><<<ggrid, 256, 0, stream>>>(S, Wt, H, nullptr, nullptr, nullptr, nullptr, nullptr,
                                          2000u + (unsigned)step, LDA);
    // z2 = h@W^T + b_mod (ext-K); dE partials; s_new ~ Bern(sigm(z2)) -> S
    gemm_bt<1><<<ggrid, 256, 0, stream>>>(H, Wb, S, nullptr, u, nullptr, p0, p1,
                                          3000u + (unsigned)step, LDA);
    // u_new ~ Bern(sigm(-p0 + 2 p1)); re-zero partials
    k_ustep<<<NB / 256, 256, 0, stream>>>(u, p0, p1, 4000u + (unsigned)step);
  }

  // Free-energy softplus sums (K=1024, plain vW accumulator + cmod read)
  gemm_bt<2><<<ggrid, 256, 0, stream>>>(V, Wt, nullptr, cmod, nullptr, wcs, spn_d, spf_d, 0u, 1024);
  gemm_bt<2><<<ggrid, 256, 0, stream>>>(S, Wt, nullptr, cmod, u, wcs, spn_m, spf_m, 0u, 1024);
  k_final<<<NB, 256, 0, stream>>>(vdata, S, bmod, u, spn_d, spf_d, spn_m, spf_m, fdiff);
  k_reduce<<<1, 256, 0, stream>>>(fdiff, out);
}

// Round 3
// 3461.103 us; speedup vs baseline: 1.1582x; 1.0855x over previous
//
#include <hip/hip_runtime.h>
#include <hip/hip_bf16.h>
#include <stdint.h>

// SymmetricHyperRBM on MI355X. K=10 Gibbs chain + free-energy gap.
// Rank-64 FiLM biases folded into GEMM K-dim: A'=[state|X|1|pad] (K=1120),
// B'=[W|G|cst|pad] -> accumulators ARE logits. dE = -sum z + 2 sum v*z.
// GEMM: 128x256 tile, bf16 MFMA 16x16x32, global_load_lds staging,
// epilogue samples repacked through LDS -> coalesced dwordx4 stores.

#define NB 16384
#define NV 1024
#define NH 1024
#define KSTEPS 10
#define LDA 1120           // 1024 + 64 (X) + 1 (const) + 31 pad
#define SLS 264            // slab row stride in ushorts (528 B, 16B-aligned, padded)

typedef __attribute__((ext_vector_type(8))) short bf16x8;
typedef __attribute__((ext_vector_type(4))) float f32x4;

__device__ __forceinline__ unsigned hash32(unsigned idx, unsigned salt) {
  unsigned x = idx + salt * 0x9E3779B9u;
  x = (x ^ (x >> 16)) * 0x7feb352du;
  x = (x ^ (x >> 15)) * 0x846ca68bu;
  return x ^ (x >> 16);
}
__device__ __forceinline__ float rng_u01(unsigned salt, unsigned idx) {
  return (float)(hash32(idx, salt) >> 8) * (1.0f / 16777216.0f);
}
// Bernoulli(sigm(z)) with 16-bit uniform f in [0,65536): r<sigm(z) <=> f*e^-z < 65536-f
__device__ __forceinline__ unsigned short bern16(float z, float f) {
  return (f * __expf(-z) < 65536.f - f) ? (unsigned short)0x3F80 : (unsigned short)0;
}
__device__ __forceinline__ float sigm(float z) { return 1.0f / (1.0f + __expf(-z)); }
__device__ __forceinline__ float softplus_(float z) {
  return z > 0.f ? z + log1pf(__expf(-z)) : log1pf(__expf(z));
}
__device__ __forceinline__ float lse2(float a, float b) {
  float m = fmaxf(a, b);
  return m + log1pf(__expf(fminf(a, b) - m));
}
__device__ __forceinline__ unsigned short f2bf(float f) {
  __hip_bfloat16 h = __float2bfloat16(f);
  return *reinterpret_cast<unsigned short*>(&h);
}
__device__ __forceinline__ void gl2lds16(const void* g, void* l) {
  __builtin_amdgcn_global_load_lds(
      (const __attribute__((address_space(1))) unsigned int*)g,
      (__attribute__((address_space(3))) unsigned int*)l, 16, 0, 0);
}

// ---------------------------------------------------------------------------
// C[16384 x 1024] = A[16384 x Kdim] * Bt[1024 x Kdim]^T, 128x256 tiles.
// EPI 0: h = bern(sigm(z)) -> sh (repacked coalesced store)
// EPI 1: p0+=sum z, p1+=sum v*z (v=u?s_old:1-s_old); s_new=bern(sigm(z)) -> sh
// EPI 2: free-energy softplus row sums (reads cmod; u-swap for model pass)
// ---------------------------------------------------------------------------
template <int EPI>
__global__ __launch_bounds__(256, 2) void gemm_bt(
    const unsigned short* __restrict__ A, const unsigned short* __restrict__ Bt,
    unsigned short* sh, const float* __restrict__ mod, const float* __restrict__ u,
    const float* __restrict__ wcs, float* __restrict__ p0, float* __restrict__ p1,
    unsigned salt, int Kdim) {
  __shared__ __align__(16) char smem[24576];  // As 8K | Bs 16K ; reused as 17K slab
  unsigned short* As = (unsigned short*)smem;
  unsigned short* Bs = (unsigned short*)(smem + 8192);
  unsigned short* sm = (unsigned short*)smem;  // epilogue slab (alias)

  const int t = threadIdx.x;
  const int m0 = blockIdx.x * 128, n0 = blockIdx.y * 256;
  const int lane = t & 63, wave = t >> 6;
  const int wm = (wave >> 1) * 64, wn = (wave & 1) * 128;
  const int lr = lane & 15, quad = lane >> 4;
  const int srw = lane >> 2, scb = (lane & 3) * 16;  // staging row / byte col

  f32x4 acc[4][8] = {};

  for (int k0 = 0; k0 < Kdim; k0 += 32) {
#pragma unroll
    for (int c = 0; c < 2; ++c) {  // A: wave stages rows [wave*32, +32)
      const int row = wave * 32 + c * 16 + srw;
      gl2lds16((const char*)(A + (size_t)(m0 + row) * LDA + k0) + scb,
               (char*)As + (wave * 32 + c * 16) * 64);
    }
#pragma unroll
    for (int c = 0; c < 4; ++c) {  // B: wave stages rows [wave*64, +64)
      const int row = wave * 64 + c * 16 + srw;
      gl2lds16((const char*)(Bt + (size_t)(n0 + row) * LDA + k0) + scb,
               (char*)Bs + (wave * 64 + c * 16) * 64);
    }
    __syncthreads();
    bf16x8 af[4], bfr[8];
#pragma unroll
    for (int i = 0; i < 4; i++) af[i] = *(const bf16x8*)(As + (wm + i * 16 + lr) * 32 + quad * 8);
#pragma unroll
    for (int j = 0; j < 8; j++) bfr[j] = *(const bf16x8*)(Bs + (wn + j * 16 + lr) * 32 + quad * 8);
#pragma unroll
    for (int i = 0; i < 4; i++)
#pragma unroll
      for (int j = 0; j < 8; j++)
        acc[i][j] = __builtin_amdgcn_mfma_f32_16x16x32_bf16(af[i], bfr[j], acc[i][j], 0, 0, 0);
    __syncthreads();
  }

  // C/D layout (m89): col = lane&15, row = quad*4 + reg
  if constexpr (EPI == 2) {
#pragma unroll
    for (int i = 0; i < 4; i++)
#pragma unroll
      for (int rg = 0; rg < 4; rg++) {
        const int r = m0 + wm + i * 16 + quad * 4 + rg;
        const bool uu = (u == nullptr) ? true : (u[r] != 0.f);
        float sn = 0.f, sf = 0.f;
#pragma unroll
        for (int j = 0; j < 8; j++) {
          const int n = n0 + wn + j * 16 + lr;
          const float vw = acc[i][j][rg];
          const float cm = mod[(size_t)r * 1024 + n];
          const float s1 = softplus_(vw + cm);
          const float s2 = softplus_(wcs[n] - vw + cm);
          sn += uu ? s1 : s2;
          sf += uu ? s2 : s1;
        }
#pragma unroll
        for (int msk = 1; msk < 16; msk <<= 1) {
          sn += __shfl_xor(sn, msk, 64);
          sf += __shfl_xor(sf, msk, 64);
        }
        if (lr == 0) { atomicAdd(&p0[r], sn); atomicAdd(&p1[r], sf); }
      }
    return;
  }

  if constexpr (EPI == 1) {  // pass 1: z-sums with v from OLD s (before overwrite)
#pragma unroll
    for (int i = 0; i < 4; i++)
#pragma unroll
      for (int rg = 0; rg < 4; rg++) {
        const int r = m0 + wm + i * 16 + quad * 4 + rg;
        const float uu = u[r];
        float q0 = 0.f, q1 = 0.f;
#pragma unroll
        for (int j = 0; j < 8; j++) {
          const int n = n0 + wn + j * 16 + lr;
          const float z = acc[i][j][rg];
          const float so = (sh[(size_t)r * LDA + n] != 0) ? 1.f : 0.f;
          const float v = (uu != 0.f) ? so : 1.f - so;
          q0 += z; q1 += v * z;
        }
#pragma unroll
        for (int msk = 1; msk < 16; msk <<= 1) {
          q0 += __shfl_xor(q0, msk, 64);
          q1 += __shfl_xor(q1, msk, 64);
        }
        if (lr == 0) { atomicAdd(&p0[r], q0); atomicAdd(&p1[r], q1); }
      }
  }

  // sample + repack through LDS -> coalesced stores (EPI 0 and 1)
#pragma unroll
  for (int s = 0; s < 4; ++s) {
    if (wm == (s >> 1) * 64) {
      const int i0 = 2 * (s & 1);
#pragma unroll
      for (int i2 = 0; i2 < 2; ++i2) {
        const int i = i0 + i2;
#pragma unroll
        for (int rg = 0; rg < 4; ++rg) {
          const int row = wm + i * 16 + quad * 4 + rg;
          const int r = m0 + row, rowl = row - s * 32;
#pragma unroll
          for (int jp = 0; jp < 4; ++jp) {
            const unsigned x = hash32((unsigned)(r << 10) + (unsigned)(n0 + wn + jp * 16 + lr), salt);
            const float flo = (float)(x & 0xFFFFu), fhi = (float)(x >> 16);
            sm[rowl * SLS + wn + jp * 16 + lr] = bern16(acc[i][jp][rg], flo);
            sm[rowl * SLS + wn + (jp + 4) * 16 + lr] = bern16(acc[i][jp + 4][rg], fhi);
          }
        }
      }
    }
    __syncthreads();
#pragma unroll
    for (int p = 0; p < 4; ++p) {  // 32 rows x 512B, coalesced
      const int c = p * 256 + t, rowl = c >> 5, chk = c & 31;
      const uint4 vv = *(const uint4*)((const char*)sm + rowl * (SLS * 2) + chk * 16);
      *(uint4*)(sh + (size_t)(m0 + s * 32 + rowl) * LDA + n0 + chk * 8) = vv;
    }
    __syncthreads();
  }
}

// ------------------------- setup / small kernels ---------------------------
__global__ __launch_bounds__(256) void k_x(const float* __restrict__ cond,
                                           const float* __restrict__ fc1w,
                                           const float* __restrict__ fc1b, float* __restrict__ X) {
  int idx = blockIdx.x * 256 + threadIdx.x;
  int r = idx >> 6, k = idx & 63;
  X[idx] = tanhf(cond[r] * fc1w[k] + fc1b[k]);
}

__global__ __launch_bounds__(256) void k_g(const float* __restrict__ fc2w,
                                           const float* __restrict__ fc2b,
                                           const float* __restrict__ b, const float* __restrict__ c,
                                           float* __restrict__ Gb, float* __restrict__ Gc,
                                           float* __restrict__ cstb, float* __restrict__ cstc) {
  int idx = blockIdx.x * 256 + threadIdx.x;
  int j = idx >> 6, k = idx & 63;
  Gb[idx] = fc2w[(size_t)j * 64 + k] * b[j] + fc2w[(size_t)(1024 + j) * 64 + k];
  Gc[idx] = fc2w[(size_t)(2048 + j) * 64 + k] * c[j] + fc2w[(size_t)(3072 + j) * 64 + k];
  if (k == 0) {
    cstb[j] = b[j] + fc2b[j] * b[j] + fc2b[1024 + j];
    cstc[j] = c[j] + fc2b[2048 + j] * c[j] + fc2b[3072 + j];
  }
}

__global__ __launch_bounds__(256) void k_prep(const float* __restrict__ W,
                                              const float* __restrict__ Gb,
                                              const float* __restrict__ Gc,
                                              const float* __restrict__ cstb,
                                              const float* __restrict__ cstc,
                                              unsigned short* __restrict__ Wt,
                                              unsigned short* __restrict__ Wb) {
  int k = blockIdx.x * 256 + threadIdx.x;
  int n = blockIdx.y;
  if (k >= LDA) return;
  unsigned short wt, wb;
  if (k < 1024) {
    wt = f2bf(W[(size_t)k * 1024 + n]);
    wb = f2bf(W[(size_t)n * 1024 + k]);
  } else if (k < 1088) {
    int j = k - 1024;
    wt = f2bf(Gc[(size_t)n * 64 + j]);
    wb = f2bf(Gb[(size_t)n * 64 + j]);
  } else if (k == 1088) {
    wt = f2bf(cstc[n]);
    wb = f2bf(cstb[n]);
  } else { wt = 0; wb = 0; }
  Wt[(size_t)n * LDA + k] = wt;
  Wb[(size_t)n * LDA + k] = wb;
}

__global__ __launch_bounds__(256) void k_wcs(const float* __restrict__ W, float* __restrict__ wcs) {
  int n = blockIdx.x * 256 + threadIdx.x;
  float s = 0.f;
  for (int i = 0; i < 1024; i++) s += W[(size_t)i * 1024 + n];
  wcs[n] = s;
}

__global__ __launch_bounds__(256) void k_bmod(const float* __restrict__ X,
                                              const float* __restrict__ G,
                                              const float* __restrict__ cst,
                                              float* __restrict__ out) {
  __shared__ __align__(16) float Xs[128 * 64];
  __shared__ __align__(16) float Gs[128 * 64];
  const int t = threadIdx.x;
  const int r0 = blockIdx.x * 128, c0 = blockIdx.y * 128;
#pragma unroll
  for (int c = 0; c < 8; ++c) {
    int i4 = c * 256 + t;
    ((float4*)Xs)[i4] = ((const float4*)(X + (size_t)r0 * 64))[i4];
    ((float4*)Gs)[i4] = ((const float4*)(G + (size_t)c0 * 64))[i4];
  }
  __syncthreads();
  const int tr = (t >> 4) * 8, tc = (t & 15) * 8;
  float acc[8][8] = {};
  for (int k = 0; k < 64; k += 4) {
    float4 xa[8], gb[8];
#pragma unroll
    for (int i = 0; i < 8; i++) xa[i] = *(const float4*)(Xs + (tr + i) * 64 + k);
#pragma unroll
    for (int j = 0; j < 8; j++) gb[j] = *(const float4*)(Gs + (tc + j) * 64 + k);
#pragma unroll
    for (int i = 0; i < 8; i++)
#pragma unroll
      for (int j = 0; j < 8; j++)
        acc[i][j] += xa[i].x * gb[j].x + xa[i].y * gb[j].y + xa[i].z * gb[j].z + xa[i].w * gb[j].w;
  }
#pragma unroll
  for (int i = 0; i < 8; i++)
#pragma unroll
    for (int j = 0; j < 8; j++)
      out[(size_t)(r0 + tr + i) * 1024 + (c0 + tc + j)] = acc[i][j] + cst[c0 + tc + j];
}

__global__ __launch_bounds__(256) void k_u0(float* __restrict__ u) {
  int r = blockIdx.x * 256 + threadIdx.x;
  u[r] = (rng_u01(0xABCD1234u, (unsigned)r) < 0.5f) ? 1.f : 0.f;
}

__global__ __launch_bounds__(256) void k_sinit(const float* __restrict__ vdata,
                                               const float* __restrict__ u,
                                               const float* __restrict__ X,
                                               unsigned short* __restrict__ S,
                                               unsigned short* __restrict__ H,
                                               unsigned short* __restrict__ V) {
  int k = blockIdx.x * 256 + threadIdx.x;
  int r = blockIdx.y;
  if (k >= LDA) return;
  const size_t o = (size_t)r * LDA + k;
  if (k < 1024) {
    float vd = vdata[(size_t)r * 1024 + k];
    V[o] = (vd != 0.f) ? (unsigned short)0x3F80 : (unsigned short)0;
    float sv = (u[r] != 0.f) ? vd : 1.f - vd;
    S[o] = (sv != 0.f) ? (unsigned short)0x3F80 : (unsigned short)0;
  } else {
    unsigned short xv;
    if (k < 1088) xv = f2bf(X[(size_t)r * 64 + (k - 1024)]);
    else if (k == 1088) xv = (unsigned short)0x3F80;
    else xv = 0;
    S[o] = xv; H[o] = xv;
  }
}

__global__ __launch_bounds__(256) void k_ustep(float* __restrict__ u, float* __restrict__ p0,
                                               float* __restrict__ p1, unsigned salt) {
  int r = blockIdx.x * 256 + threadIdx.x;
  float dE = -p0[r] + 2.f * p1[r];
  u[r] = (rng_u01(salt, (unsigned)r) < sigm(dE)) ? 1.f : 0.f;
  p0[r] = 0.f; p1[r] = 0.f;
}

__global__ __launch_bounds__(256) void k_final(
    const float* __restrict__ vdata, const unsigned short* __restrict__ S,
    const float* __restrict__ bmod, const float* __restrict__ u,
    const float* __restrict__ spn_d, const float* __restrict__ spf_d,
    const float* __restrict__ spn_m, const float* __restrict__ spf_m, float* __restrict__ fdiff) {
  __shared__ float red0[4], red1[4], red2[4];
  int r = blockIdx.x, t = threadIdx.x;
  const float* brow = bmod + (size_t)r * 1024;
  const float* vrow = vdata + (size_t)r * 1024;
  const unsigned short* srow = S + (size_t)r * LDA;
  float d0 = 0.f, d1 = 0.f, d2 = 0.f;
  for (int j = t; j < 1024; j += 256) {
    float bm = brow[j];
    d0 += bm;
    d1 += vrow[j] * bm;
    d2 += (srow[j] != 0) ? bm : 0.f;
  }
  for (int m = 32; m >= 1; m >>= 1) {
    d0 += __shfl_xor(d0, m, 64);
    d1 += __shfl_xor(d1, m, 64);
    d2 += __shfl_xor(d2, m, 64);
  }
  if ((t & 63) == 0) { red0[t >> 6] = d0; red1[t >> 6] = d1; red2[t >> 6] = d2; }
  __syncthreads();
  if (t == 0) {
    d0 = red0[0] + red0[1] + red0[2] + red0[3];
    d1 = red1[0] + red1[1] + red1[2] + red1[3];
    d2 = red2[0] + red2[1] + red2[2] + red2[3];
    float Fn_d = -d1 - spn_d[r];
    float Ff_d = -(d0 - d1) - spf_d[r];
    float F_d = -lse2(-Fn_d, -Ff_d);
    float vbn = (u[r] != 0.f) ? d2 : (d0 - d2);
    float Fn_m = -vbn - spn_m[r];
    float Ff_m = -(d0 - vbn) - spf_m[r];
    float F_m = -lse2(-Fn_m, -Ff_m);
    fdiff[r] = F_d - F_m;
  }
}

__global__ __launch_bounds__(256) void k_reduce(const float* __restrict__ fdiff,
                                                float* __restrict__ out) {
  __shared__ float red[4];
  int t = threadIdx.x;
  float s = 0.f;
  for (int i = t; i < NB; i += 256) s += fdiff[i];
  for (int m = 32; m >= 1; m >>= 1) s += __shfl_xor(s, m, 64);
  if ((t & 63) == 0) red[t >> 6] = s;
  __syncthreads();
  if (t == 0) out[0] = (red[0] + red[1] + red[2] + red[3]) * (1.0f / (float)NB);
}

// ---------------------------------------------------------------------------
extern "C" void kernel_launch(void* const* d_in, const int* in_sizes, int n_in, void* d_out,
                              int out_size, void* d_ws, size_t ws_size, hipStream_t stream) {
  const float* vdata = (const float*)d_in[0];
  const float* cond = (const float*)d_in[1];
  const float* W = (const float*)d_in[2];
  const float* bb = (const float*)d_in[3];
  const float* cc = (const float*)d_in[4];
  const float* fc1w = (const float*)d_in[5];
  const float* fc1b = (const float*)d_in[6];
  const float* fc2w = (const float*)d_in[7];
  const float* fc2b = (const float*)d_in[8];
  float* out = (float*)d_out;

  char* wp = (char*)d_ws;
  auto alloc = [&](size_t bytes) {
    char* p = wp;
    wp += (bytes + 255) & ~(size_t)255;
    return p;
  };
  unsigned short* Wt = (unsigned short*)alloc((size_t)1024 * LDA * 2);
  unsigned short* Wb = (unsigned short*)alloc((size_t)1024 * LDA * 2);
  float* wcs = (float*)alloc(1024 * 4);
  float* X = (float*)alloc((size_t)NB * 64 * 4);
  float* Gb = (float*)alloc((size_t)1024 * 64 * 4);
  float* Gc = (float*)alloc((size_t)1024 * 64 * 4);
  float* cstb = (float*)alloc(1024 * 4);
  float* cstc = (float*)alloc(1024 * 4);
  float* bmod = (float*)alloc((size_t)NB * 1024 * 4);
  float* cmod = (float*)alloc((size_t)NB * 1024 * 4);
  float* u = (float*)alloc(NB * 4);
  unsigned short* S = (unsigned short*)alloc((size_t)NB * LDA * 2);
  unsigned short* H = (unsigned short*)alloc((size_t)NB * LDA * 2);
  unsigned short* V = (unsigned short*)alloc((size_t)NB * LDA * 2);
  float* p0 = (float*)alloc(NB * 4);  // contiguous: p0,p1,spn_d,spf_d,spn_m,spf_m
  float* p1 = (float*)alloc(NB * 4);
  float* spn_d = (float*)alloc(NB * 4);
  float* spf_d = (float*)alloc(NB * 4);
  float* spn_m = (float*)alloc(NB * 4);
  float* spf_m = (float*)alloc(NB * 4);
  float* fdiff = (float*)alloc(NB * 4);

  hipMemsetAsync(p0, 0, (size_t)NB * 4 * 6, stream);

  k_x<<<NB * 64 / 256, 256, 0, stream>>>(cond, fc1w, fc1b, X);
  k_g<<<1024 * 64 / 256, 256, 0, stream>>>(fc2w, fc2b, bb, cc, Gb, Gc, cstb, cstc);
  k_prep<<<dim3(5, 1024), 256, 0, stream>>>(W, Gb, Gc, cstb, cstc, Wt, Wb);
  k_wcs<<<4, 256, 0, stream>>>(W, wcs);
  dim3 bgrid(NB / 128, 1024 / 128);
  k_bmod<<<bgrid, 256, 0, stream>>>(X, Gb, cstb, bmod);
  k_bmod<<<bgrid, 256, 0, stream>>>(X, Gc, cstc, cmod);
  k_u0<<<NB / 256, 256, 0, stream>>>(u);
  k_sinit<<<dim3(5, NB), 256, 0, stream>>>(vdata, u, X, S, H, V);

  dim3 ggrid(NB / 128, 1024 / 256);
  for (int step = 0; step < KSTEPS; ++step) {
    gemm_bt<0><<<ggrid, 256, 0, stream>>>(S, Wt, H, nullptr, nullptr, nullptr, nullptr, nullptr,
                                          2000u + (unsigned)step, LDA);
    gemm_bt<1><<<ggrid, 256, 0, stream>>>(H, Wb, S, nullptr, u, nullptr, p0, p1,
                                          3000u + (unsigned)step, LDA);
    k_ustep<<<NB / 256, 256, 0, stream>>>(u, p0, p1, 4000u + (unsigned)step);
  }

  gemm_bt<2><<<ggrid, 256, 0, stream>>>(V, Wt, nullptr, cmod, nullptr, wcs, spn_d, spf_d, 0u, 1024);
  gemm_bt<2><<<ggrid, 256, 0, stream>>>(S, Wt, nullptr, cmod, u, wcs, spn_m, spf_m, 0u, 1024);
  k_final<<<NB, 256, 0, stream>>>(vdata, S, bmod, u, spn_d, spf_d, spn_m, spf_m, fdiff);
  k_reduce<<<1, 256, 0, stream>>>(fdiff, out);
}

// Round 4
// 2438.354 us; speedup vs baseline: 1.6440x; 1.4194x over previous
//
#include <hip/hip_runtime.h>
#include <hip/hip_bf16.h>
#include <stdint.h>

// SymmetricHyperRBM on MI355X. K=10 Gibbs chain + free-energy gap.
// Rank-64 FiLM biases folded into GEMM K-dim: A'=[state|X|1|pad] (K=1152),
// B'=[W|G|cst|pad] -> accumulators ARE logits. dE = -sum z + 2 sum v*z.
// GEMM: 128x128 tile (4 blocks/CU), BK=64 (two BK=32 half-slabs in LDS),
// global_load_lds width-16 staging, epilogue repack -> coalesced stores.

#define NB 16384
#define NV 1024
#define NH 1024
#define KSTEPS 10
#define LDA 1152           // 1024 + 64 (X) + 1 (const) + 63 pad; 18 K-iters of 64
#define SLS 132            // epilogue slab row stride in ushorts (264 B)

typedef __attribute__((ext_vector_type(8))) short bf16x8;
typedef __attribute__((ext_vector_type(4))) float f32x4;

__device__ __forceinline__ unsigned hash32(unsigned idx, unsigned salt) {
  unsigned x = idx + salt * 0x9E3779B9u;
  x = (x ^ (x >> 16)) * 0x7feb352du;
  x = (x ^ (x >> 15)) * 0x846ca68bu;
  return x ^ (x >> 16);
}
__device__ __forceinline__ float rng_u01(unsigned salt, unsigned idx) {
  return (float)(hash32(idx, salt) >> 8) * (1.0f / 16777216.0f);
}
// Bernoulli(sigm(z)) with 16-bit uniform f in [0,65536): r<sigm(z) <=> f*e^-z < 65536-f
__device__ __forceinline__ unsigned short bern16(float z, float f) {
  return (f * __expf(-z) < 65536.f - f) ? (unsigned short)0x3F80 : (unsigned short)0;
}
__device__ __forceinline__ float sigm(float z) { return 1.0f / (1.0f + __expf(-z)); }
__device__ __forceinline__ float softplus_(float z) {
  return z > 0.f ? z + log1pf(__expf(-z)) : log1pf(__expf(z));
}
__device__ __forceinline__ float lse2(float a, float b) {
  float m = fmaxf(a, b);
  return m + log1pf(__expf(fminf(a, b) - m));
}
__device__ __forceinline__ unsigned short f2bf(float f) {
  __hip_bfloat16 h = __float2bfloat16(f);
  return *reinterpret_cast<unsigned short*>(&h);
}
__device__ __forceinline__ void gl2lds16(const void* g, void* l) {
  __builtin_amdgcn_global_load_lds(
      (const __attribute__((address_space(1))) unsigned int*)g,
      (__attribute__((address_space(3))) unsigned int*)l, 16, 0, 0);
}

// ---------------------------------------------------------------------------
// C[16384 x 1024] = A[16384 x Kdim] * Bt[1024 x Kdim]^T, 128x128 tiles, BK=64.
// EPI 0: h = bern(sigm(z)) -> sh (slab-repacked coalesced store)
// EPI 1: p0+=sum z, p1+=sum v*z (v=u?s_old:1-s_old); s_new=bern(sigm(z)) -> sh
// EPI 2: free-energy softplus row sums (reads cmod; u-swap for model pass)
// ---------------------------------------------------------------------------
template <int EPI>
__global__ __launch_bounds__(256, 4) void gemm_bt(
    const unsigned short* __restrict__ A, const unsigned short* __restrict__ Bt,
    unsigned short* sh, const float* __restrict__ mod, const float* __restrict__ u,
    const float* __restrict__ wcs, float* __restrict__ p0, float* __restrict__ p1,
    unsigned salt, int Kdim) {
  // staging: A half0 [0,8K) A half1 [8K,16K) B half0 [16K,24K) B half1 [24K,32K)
  // epilogue: slab 64 x 264 B = 16.9 KB aliases the front.
  __shared__ __align__(16) char smem[32768];
  unsigned short* sm = (unsigned short*)smem;

  const int t = threadIdx.x;
  const int m0 = blockIdx.x * 128, n0 = blockIdx.y * 128;
  const int lane = t & 63, wave = t >> 6;
  const int wm = (wave >> 1) * 64, wn = (wave & 1) * 64;
  const int lr = lane & 15, quad = lane >> 4;
  const int r4 = lane >> 2, c4 = lane & 3;  // staging: 16 rows x 4 chunks of 16B

  f32x4 acc[4][4] = {};

  for (int k0 = 0; k0 < Kdim; k0 += 64) {
#pragma unroll
    for (int c = 0; c < 2; ++c) {
      const int row = wave * 32 + c * 16 + r4;
      const unsigned short* ga = A + (size_t)(m0 + row) * LDA + k0 + c4 * 8;
      const unsigned short* gb = Bt + (size_t)(n0 + row) * LDA + k0 + c4 * 8;
      char* la = smem + (wave * 32 + c * 16) * 64;
      gl2lds16(ga, la);                      // A k-half 0
      gl2lds16(ga + 32, la + 8192);          // A k-half 1
      gl2lds16(gb, la + 16384);              // B k-half 0
      gl2lds16(gb + 32, la + 24576);         // B k-half 1
    }
    __syncthreads();
#pragma unroll
    for (int s = 0; s < 2; ++s) {
      const unsigned short* Ah = (const unsigned short*)(smem + s * 8192);
      const unsigned short* Bh = (const unsigned short*)(smem + 16384 + s * 8192);
      bf16x8 af[4], bfr[4];
#pragma unroll
      for (int i = 0; i < 4; i++) af[i] = *(const bf16x8*)(Ah + (wm + i * 16 + lr) * 32 + quad * 8);
#pragma unroll
      for (int j = 0; j < 4; j++) bfr[j] = *(const bf16x8*)(Bh + (wn + j * 16 + lr) * 32 + quad * 8);
#pragma unroll
      for (int i = 0; i < 4; i++)
#pragma unroll
        for (int j = 0; j < 4; j++)
          acc[i][j] = __builtin_amdgcn_mfma_f32_16x16x32_bf16(af[i], bfr[j], acc[i][j], 0, 0, 0);
    }
    __syncthreads();
  }

  // C/D layout (m89): col = lane&15, row = quad*4 + reg
  if constexpr (EPI == 2) {
#pragma unroll
    for (int i = 0; i < 4; i++)
#pragma unroll
      for (int rg = 0; rg < 4; rg++) {
        const int r = m0 + wm + i * 16 + quad * 4 + rg;
        const bool uu = (u == nullptr) ? true : (u[r] != 0.f);
        float sn = 0.f, sf = 0.f;
#pragma unroll
        for (int j = 0; j < 4; j++) {
          const int n = n0 + wn + j * 16 + lr;
          const float vw = acc[i][j][rg];
          const float cm = mod[(size_t)r * 1024 + n];
          const float s1 = softplus_(vw + cm);
          const float s2 = softplus_(wcs[n] - vw + cm);
          sn += uu ? s1 : s2;
          sf += uu ? s2 : s1;
        }
#pragma unroll
        for (int msk = 1; msk < 16; msk <<= 1) {
          sn += __shfl_xor(sn, msk, 64);
          sf += __shfl_xor(sf, msk, 64);
        }
        if (lr == 0) { atomicAdd(&p0[r], sn); atomicAdd(&p1[r], sf); }
      }
    return;
  }

  if constexpr (EPI == 1) {  // z-sums with v from OLD s (read before overwrite)
#pragma unroll
    for (int i = 0; i < 4; i++)
#pragma unroll
      for (int rg = 0; rg < 4; rg++) {
        const int r = m0 + wm + i * 16 + quad * 4 + rg;
        const float uu = u[r];
        float q0 = 0.f, q1 = 0.f;
#pragma unroll
        for (int j = 0; j < 4; j++) {
          const int n = n0 + wn + j * 16 + lr;
          const float z = acc[i][j][rg];
          const float so = (sh[(size_t)r * LDA + n] != 0) ? 1.f : 0.f;
          const float v = (uu != 0.f) ? so : 1.f - so;
          q0 += z; q1 += v * z;
        }
#pragma unroll
        for (int msk = 1; msk < 16; msk <<= 1) {
          q0 += __shfl_xor(q0, msk, 64);
          q1 += __shfl_xor(q1, msk, 64);
        }
        if (lr == 0) { atomicAdd(&p0[r], q0); atomicAdd(&p1[r], q1); }
      }
  }

  // sample + repack through LDS -> coalesced stores (EPI 0 and 1)
  const int myphase = wm >> 6;  // waves 0,1 -> rows 0..63 ; waves 2,3 -> 64..127
#pragma unroll
  for (int ph = 0; ph < 2; ++ph) {
    if (myphase == ph) {
#pragma unroll
      for (int i = 0; i < 4; ++i)
#pragma unroll
        for (int rg = 0; rg < 4; ++rg) {
          const int rowl = i * 16 + quad * 4 + rg;  // 0..63 within phase
          const int r = m0 + wm + rowl;
#pragma unroll
          for (int jp = 0; jp < 2; ++jp) {
            const unsigned x =
                hash32((unsigned)(r << 10) + (unsigned)(n0 + wn + jp * 16 + lr), salt);
            const float flo = (float)(x & 0xFFFFu), fhi = (float)(x >> 16);
            sm[rowl * SLS + wn + jp * 16 + lr] = bern16(acc[i][jp][rg], flo);
            sm[rowl * SLS + wn + (jp + 2) * 16 + lr] = bern16(acc[i][jp + 2][rg], fhi);
          }
        }
    }
    __syncthreads();
#pragma unroll
    for (int p = 0; p < 4; ++p) {  // 64 rows x 256 B, fully coalesced
      const int c = p * 256 + t, rowl = c >> 4, chk = c & 15;
      const uint4 vv = *(const uint4*)((const char*)sm + rowl * (SLS * 2) + chk * 16);
      *(uint4*)(sh + (size_t)(m0 + ph * 64 + rowl) * LDA + n0 + chk * 8) = vv;
    }
    __syncthreads();
  }
}

// ------------------------- setup / small kernels ---------------------------
__global__ __launch_bounds__(256) void k_x(const float* __restrict__ cond,
                                           const float* __restrict__ fc1w,
                                           const float* __restrict__ fc1b, float* __restrict__ X) {
  int idx = blockIdx.x * 256 + threadIdx.x;
  int r = idx >> 6, k = idx & 63;
  X[idx] = tanhf(cond[r] * fc1w[k] + fc1b[k]);
}

__global__ __launch_bounds__(256) void k_g(const float* __restrict__ fc2w,
                                           const float* __restrict__ fc2b,
                                           const float* __restrict__ b, const float* __restrict__ c,
                                           float* __restrict__ Gb, float* __restrict__ Gc,
                                           float* __restrict__ cstb, float* __restrict__ cstc) {
  int idx = blockIdx.x * 256 + threadIdx.x;
  int j = idx >> 6, k = idx & 63;
  Gb[idx] = fc2w[(size_t)j * 64 + k] * b[j] + fc2w[(size_t)(1024 + j) * 64 + k];
  Gc[idx] = fc2w[(size_t)(2048 + j) * 64 + k] * c[j] + fc2w[(size_t)(3072 + j) * 64 + k];
  if (k == 0) {
    cstb[j] = b[j] + fc2b[j] * b[j] + fc2b[1024 + j];
    cstc[j] = c[j] + fc2b[2048 + j] * c[j] + fc2b[3072 + j];
  }
}

__global__ __launch_bounds__(256) void k_prep(const float* __restrict__ W,
                                              const float* __restrict__ Gb,
                                              const float* __restrict__ Gc,
                                              const float* __restrict__ cstb,
                                              const float* __restrict__ cstc,
                                              unsigned short* __restrict__ Wt,
                                              unsigned short* __restrict__ Wb) {
  int k = blockIdx.x * 256 + threadIdx.x;
  int n = blockIdx.y;
  if (k >= LDA) return;
  unsigned short wt, wb;
  if (k < 1024) {
    wt = f2bf(W[(size_t)k * 1024 + n]);
    wb = f2bf(W[(size_t)n * 1024 + k]);
  } else if (k < 1088) {
    int j = k - 1024;
    wt = f2bf(Gc[(size_t)n * 64 + j]);
    wb = f2bf(Gb[(size_t)n * 64 + j]);
  } else if (k == 1088) {
    wt = f2bf(cstc[n]);
    wb = f2bf(cstb[n]);
  } else { wt = 0; wb = 0; }
  Wt[(size_t)n * LDA + k] = wt;
  Wb[(size_t)n * LDA + k] = wb;
}

__global__ __launch_bounds__(256) void k_wcs(const float* __restrict__ W, float* __restrict__ wcs) {
  int n = blockIdx.x * 256 + threadIdx.x;
  float s = 0.f;
  for (int i = 0; i < 1024; i++) s += W[(size_t)i * 1024 + n];
  wcs[n] = s;
}

__global__ __launch_bounds__(256) void k_bmod(const float* __restrict__ X,
                                              const float* __restrict__ G,
                                              const float* __restrict__ cst,
                                              float* __restrict__ out) {
  __shared__ __align__(16) float Xs[128 * 64];
  __shared__ __align__(16) float Gs[128 * 64];
  const int t = threadIdx.x;
  const int r0 = blockIdx.x * 128, c0 = blockIdx.y * 128;
#pragma unroll
  for (int c = 0; c < 8; ++c) {
    int i4 = c * 256 + t;
    ((float4*)Xs)[i4] = ((const float4*)(X + (size_t)r0 * 64))[i4];
    ((float4*)Gs)[i4] = ((const float4*)(G + (size_t)c0 * 64))[i4];
  }
  __syncthreads();
  const int tr = (t >> 4) * 8, tc = (t & 15) * 8;
  float acc[8][8] = {};
  for (int k = 0; k < 64; k += 4) {
    float4 xa[8], gb[8];
#pragma unroll
    for (int i = 0; i < 8; i++) xa[i] = *(const float4*)(Xs + (tr + i) * 64 + k);
#pragma unroll
    for (int j = 0; j < 8; j++) gb[j] = *(const float4*)(Gs + (tc + j) * 64 + k);
#pragma unroll
    for (int i = 0; i < 8; i++)
#pragma unroll
      for (int j = 0; j < 8; j++)
        acc[i][j] += xa[i].x * gb[j].x + xa[i].y * gb[j].y + xa[i].z * gb[j].z + xa[i].w * gb[j].w;
  }
#pragma unroll
  for (int i = 0; i < 8; i++)
#pragma unroll
    for (int j = 0; j < 8; j++)
      out[(size_t)(r0 + tr + i) * 1024 + (c0 + tc + j)] = acc[i][j] + cst[c0 + tc + j];
}

__global__ __launch_bounds__(256) void k_u0(float* __restrict__ u) {
  int r = blockIdx.x * 256 + threadIdx.x;
  u[r] = (rng_u01(0xABCD1234u, (unsigned)r) < 0.5f) ? 1.f : 0.f;
}

__global__ __launch_bounds__(256) void k_sinit(const float* __restrict__ vdata,
                                               const float* __restrict__ u,
                                               const float* __restrict__ X,
                                               unsigned short* __restrict__ S,
                                               unsigned short* __restrict__ H,
                                               unsigned short* __restrict__ V) {
  int k = blockIdx.x * 256 + threadIdx.x;
  int r = blockIdx.y;
  if (k >= LDA) return;
  const size_t o = (size_t)r * LDA + k;
  if (k < 1024) {
    float vd = vdata[(size_t)r * 1024 + k];
    V[o] = (vd != 0.f) ? (unsigned short)0x3F80 : (unsigned short)0;
    float sv = (u[r] != 0.f) ? vd : 1.f - vd;
    S[o] = (sv != 0.f) ? (unsigned short)0x3F80 : (unsigned short)0;
  } else {
    unsigned short xv;
    if (k < 1088) xv = f2bf(X[(size_t)r * 64 + (k - 1024)]);
    else if (k == 1088) xv = (unsigned short)0x3F80;
    else xv = 0;
    S[o] = xv; H[o] = xv;
  }
}

__global__ __launch_bounds__(256) void k_ustep(float* __restrict__ u, float* __restrict__ p0,
                                               float* __restrict__ p1, unsigned salt) {
  int r = blockIdx.x * 256 + threadIdx.x;
  float dE = -p0[r] + 2.f * p1[r];
  u[r] = (rng_u01(salt, (unsigned)r) < sigm(dE)) ? 1.f : 0.f;
  p0[r] = 0.f; p1[r] = 0.f;
}

__global__ __launch_bounds__(256) void k_final(
    const float* __restrict__ vdata, const unsigned short* __restrict__ S,
    const float* __restrict__ bmod, const float* __restrict__ u,
    const float* __restrict__ spn_d, const float* __restrict__ spf_d,
    const float* __restrict__ spn_m, const float* __restrict__ spf_m, float* __restrict__ fdiff) {
  __shared__ float red0[4], red1[4], red2[4];
  int r = blockIdx.x, t = threadIdx.x;
  const float* brow = bmod + (size_t)r * 1024;
  const float* vrow = vdata + (size_t)r * 1024;
  const unsigned short* srow = S + (size_t)r * LDA;
  float d0 = 0.f, d1 = 0.f, d2 = 0.f;
  for (int j = t; j < 1024; j += 256) {
    float bm = brow[j];
    d0 += bm;
    d1 += vrow[j] * bm;
    d2 += (srow[j] != 0) ? bm : 0.f;
  }
  for (int m = 32; m >= 1; m >>= 1) {
    d0 += __shfl_xor(d0, m, 64);
    d1 += __shfl_xor(d1, m, 64);
    d2 += __shfl_xor(d2, m, 64);
  }
  if ((t & 63) == 0) { red0[t >> 6] = d0; red1[t >> 6] = d1; red2[t >> 6] = d2; }
  __syncthreads();
  if (t == 0) {
    d0 = red0[0] + red0[1] + red0[2] + red0[3];
    d1 = red1[0] + red1[1] + red1[2] + red1[3];
    d2 = red2[0] + red2[1] + red2[2] + red2[3];
    float Fn_d = -d1 - spn_d[r];
    float Ff_d = -(d0 - d1) - spf_d[r];
    float F_d = -lse2(-Fn_d, -Ff_d);
    float vbn = (u[r] != 0.f) ? d2 : (d0 - d2);
    float Fn_m = -vbn - spn_m[r];
    float Ff_m = -(d0 - vbn) - spf_m[r];
    float F_m = -lse2(-Fn_m, -Ff_m);
    fdiff[r] = F_d - F_m;
  }
}

__global__ __launch_bounds__(256) void k_reduce(const float* __restrict__ fdiff,
                                                float* __restrict__ out) {
  __shared__ float red[4];
  int t = threadIdx.x;
  float s = 0.f;
  for (int i = t; i < NB; i += 256) s += fdiff[i];
  for (int m = 32; m >= 1; m >>= 1) s += __shfl_xor(s, m, 64);
  if ((t & 63) == 0) red[t >> 6] = s;
  __syncthreads();
  if (t == 0) out[0] = (red[0] + red[1] + red[2] + red[3]) * (1.0f / (float)NB);
}

// ---------------------------------------------------------------------------
extern "C" void kernel_launch(void* const* d_in, const int* in_sizes, int n_in, void* d_out,
                              int out_size, void* d_ws, size_t ws_size, hipStream_t stream) {
  const float* vdata = (const float*)d_in[0];
  const float* cond = (const float*)d_in[1];
  const float* W = (const float*)d_in[2];
  const float* bb = (const float*)d_in[3];
  const float* cc = (const float*)d_in[4];
  const float* fc1w = (const float*)d_in[5];
  const float* fc1b = (const float*)d_in[6];
  const float* fc2w = (const float*)d_in[7];
  const float* fc2b = (const float*)d_in[8];
  float* out = (float*)d_out;

  char* wp = (char*)d_ws;
  auto alloc = [&](size_t bytes) {
    char* p = wp;
    wp += (bytes + 255) & ~(size_t)255;
    return p;
  };
  unsigned short* Wt = (unsigned short*)alloc((size_t)1024 * LDA * 2);
  unsigned short* Wb = (unsigned short*)alloc((size_t)1024 * LDA * 2);
  float* wcs = (float*)alloc(1024 * 4);
  float* X = (float*)alloc((size_t)NB * 64 * 4);
  float* Gb = (float*)alloc((size_t)1024 * 64 * 4);
  float* Gc = (float*)alloc((size_t)1024 * 64 * 4);
  float* cstb = (float*)alloc(1024 * 4);
  float* cstc = (float*)alloc(1024 * 4);
  float* bmod = (float*)alloc((size_t)NB * 1024 * 4);
  float* cmod = (float*)alloc((size_t)NB * 1024 * 4);
  float* u = (float*)alloc(NB * 4);
  unsigned short* S = (unsigned short*)alloc((size_t)NB * LDA * 2);
  unsigned short* H = (unsigned short*)alloc((size_t)NB * LDA * 2);
  unsigned short* V = (unsigned short*)alloc((size_t)NB * LDA * 2);
  float* p0 = (float*)alloc(NB * 4);  // contiguous: p0,p1,spn_d,spf_d,spn_m,spf_m
  float* p1 = (float*)alloc(NB * 4);
  float* spn_d = (float*)alloc(NB * 4);
  float* spf_d = (float*)alloc(NB * 4);
  float* spn_m = (float*)alloc(NB * 4);
  float* spf_m = (float*)alloc(NB * 4);
  float* fdiff = (float*)alloc(NB * 4);

  hipMemsetAsync(p0, 0, (size_t)NB * 4 * 6, stream);

  k_x<<<NB * 64 / 256, 256, 0, stream>>>(cond, fc1w, fc1b, X);
  k_g<<<1024 * 64 / 256, 256, 0, stream>>>(fc2w, fc2b, bb, cc, Gb, Gc, cstb, cstc);
  k_prep<<<dim3(5, 1024), 256, 0, stream>>>(W, Gb, Gc, cstb, cstc, Wt, Wb);
  k_wcs<<<4, 256, 0, stream>>>(W, wcs);
  dim3 bgrid(NB / 128, 1024 / 128);
  k_bmod<<<bgrid, 256, 0, stream>>>(X, Gb, cstb, bmod);
  k_bmod<<<bgrid, 256, 0, stream>>>(X, Gc, cstc, cmod);
  k_u0<<<NB / 256, 256, 0, stream>>>(u);
  k_sinit<<<dim3(5, NB), 256, 0, stream>>>(vdata, u, X, S, H, V);

  dim3 ggrid(NB / 128, 1024 / 128);
  for (int step = 0; step < KSTEPS; ++step) {
    gemm_bt<0><<<ggrid, 256, 0, stream>>>(S, Wt, H, nullptr, nullptr, nullptr, nullptr, nullptr,
                                          2000u + (unsigned)step, LDA);
    gemm_bt<1><<<ggrid, 256, 0, stream>>>(H, Wb, S, nullptr, u, nullptr, p0, p1,
                                          3000u + (unsigned)step, LDA);
    k_ustep<<<NB / 256, 256, 0, stream>>>(u, p0, p1, 4000u + (unsigned)step);
  }

  gemm_bt<2><<<ggrid, 256, 0, stream>>>(V, Wt, nullptr, cmod, nullptr, wcs, spn_d, spf_d, 0u, 1024);
  gemm_bt<2><<<ggrid, 256, 0, stream>>>(S, Wt, nullptr, cmod, u, wcs, spn_m, spf_m, 0u, 1024);
  k_final<<<NB, 256, 0, stream>>>(vdata, S, bmod, u, spn_d, spf_d, spn_m, spf_m, fdiff);
  k_reduce<<<1, 256, 0, stream>>>(fdiff, out);
}

// Round 5
// 2333.127 us; speedup vs baseline: 1.7181x; 1.0451x over previous
//
#include <hip/hip_runtime.h>
#include <hip/hip_bf16.h>
#include <stdint.h>

// SymmetricHyperRBM on MI355X. K=10 Gibbs chain + free-energy gap.
// Rank-64 FiLM biases folded into GEMM K-dim: A'=[state|X|1|pad] (K=1152),
// B'=[W|G|cst|pad] -> accumulators ARE logits. dE = -sum z + 2 sum v*z.
// GEMM: 128x128 tile, BK=64, global_load_lds staging, XCD-aware swizzle
// (XCD k owns one contiguous m-stripe -> A-stripe stays in its L2),
// u-chain folded into GEMM epilogues via per-step dE accumulator pairs.

#define NB 16384
#define NV 1024
#define NH 1024
#define KSTEPS 10
#define LDA 1152           // 1024 + 64 (X) + 1 (const) + 63 pad; K-iters of 64
#define SLS 132            // epilogue slab row stride in ushorts (264 B)
#define USALT 4000u

typedef __attribute__((ext_vector_type(8))) short bf16x8;
typedef __attribute__((ext_vector_type(4))) float f32x4;

__device__ __forceinline__ unsigned hash32(unsigned idx, unsigned salt) {
  unsigned x = idx + salt * 0x9E3779B9u;
  x = (x ^ (x >> 16)) * 0x7feb352du;
  x = (x ^ (x >> 15)) * 0x846ca68bu;
  return x ^ (x >> 16);
}
__device__ __forceinline__ float rng_u01(unsigned salt, unsigned idx) {
  return (float)(hash32(idx, salt) >> 8) * (1.0f / 16777216.0f);
}
// Bernoulli(sigm(z)) with 16-bit uniform f in [0,65536): r<sigm(z) <=> f*e^-z < 65536-f
__device__ __forceinline__ unsigned short bern16(float z, float f) {
  return (f * __expf(-z) < 65536.f - f) ? (unsigned short)0x3F80 : (unsigned short)0;
}
__device__ __forceinline__ float sigm(float z) { return 1.0f / (1.0f + __expf(-z)); }
__device__ __forceinline__ float softplus_(float z) {
  return z > 0.f ? z + log1pf(__expf(-z)) : log1pf(__expf(z));
}
__device__ __forceinline__ float lse2(float a, float b) {
  float m = fmaxf(a, b);
  return m + log1pf(__expf(fminf(a, b) - m));
}
__device__ __forceinline__ unsigned short f2bf(float f) {
  __hip_bfloat16 h = __float2bfloat16(f);
  return *reinterpret_cast<unsigned short*>(&h);
}
__device__ __forceinline__ float bf2f(unsigned short s) {
  unsigned u = ((unsigned)s) << 16;
  return *reinterpret_cast<float*>(&u);
}
__device__ __forceinline__ void gl2lds16(const void* g, void* l) {
  __builtin_amdgcn_global_load_lds(
      (const __attribute__((address_space(1))) unsigned int*)g,
      (__attribute__((address_space(3))) unsigned int*)l, 16, 0, 0);
}

// ---------------------------------------------------------------------------
// C[16384 x 1024] = A[16384 x Kdim] * Bt[1024 x Kdim]^T, 128x128 tiles, BK=64.
// 1D grid 1024, XCD-swizzled: L -> xcd=L&7 owns m-stripe [xcd*2048, +2048).
// EPI 0: h = bern(sigm(z)) -> sh
// EPI 1: u_t[r] inline from (pv0,pv1,usalt); p0+=sum z, p1+=sum v*z
//        (v = u_t ? s_old : 1-s_old); s_new = bern(sigm(z)) -> sh
// EPI 2: free-energy softplus row sums (mod=cmod bf16; u inline or null=data)
// ---------------------------------------------------------------------------
template <int EPI>
__global__ __launch_bounds__(256, 4) void gemm_bt(
    const unsigned short* __restrict__ A, const unsigned short* __restrict__ Bt,
    unsigned short* sh, const unsigned short* __restrict__ mod,
    const float* __restrict__ wcs,
    const float* __restrict__ pv0, const float* __restrict__ pv1, unsigned usalt,
    float* __restrict__ p0, float* __restrict__ p1, unsigned salt, int Kdim) {
  // staging: A half0 [0,8K) A half1 [8K,16K) B half0 [16K,24K) B half1 [24K,32K)
  __shared__ __align__(16) char smem[32768];
  unsigned short* sm = (unsigned short*)smem;  // epilogue slab alias (64 x 264 B)

  const int t = threadIdx.x;
  const int L = blockIdx.x;
  const int xcd = L & 7, li = L >> 3;
  const int m0 = (xcd * 16 + (li >> 3)) * 128;
  const int n0 = (li & 7) * 128;
  const int lane = t & 63, wave = t >> 6;
  const int wm = (wave >> 1) * 64, wn = (wave & 1) * 64;
  const int lr = lane & 15, quad = lane >> 4;
  const int r4 = lane >> 2, c4 = lane & 3;

  f32x4 acc[4][4] = {};

  for (int k0 = 0; k0 < Kdim; k0 += 64) {
#pragma unroll
    for (int c = 0; c < 2; ++c) {
      const int row = wave * 32 + c * 16 + r4;
      const unsigned short* ga = A + (size_t)(m0 + row) * LDA + k0 + c4 * 8;
      const unsigned short* gb = Bt + (size_t)(n0 + row) * LDA + k0 + c4 * 8;
      char* la = smem + (wave * 32 + c * 16) * 64;
      gl2lds16(ga, la);
      gl2lds16(ga + 32, la + 8192);
      gl2lds16(gb, la + 16384);
      gl2lds16(gb + 32, la + 24576);
    }
    __syncthreads();
#pragma unroll
    for (int s = 0; s < 2; ++s) {
      const unsigned short* Ah = (const unsigned short*)(smem + s * 8192);
      const unsigned short* Bh = (const unsigned short*)(smem + 16384 + s * 8192);
      bf16x8 af[4], bfr[4];
#pragma unroll
      for (int i = 0; i < 4; i++) af[i] = *(const bf16x8*)(Ah + (wm + i * 16 + lr) * 32 + quad * 8);
#pragma unroll
      for (int j = 0; j < 4; j++) bfr[j] = *(const bf16x8*)(Bh + (wn + j * 16 + lr) * 32 + quad * 8);
#pragma unroll
      for (int i = 0; i < 4; i++)
#pragma unroll
        for (int j = 0; j < 4; j++)
          acc[i][j] = __builtin_amdgcn_mfma_f32_16x16x32_bf16(af[i], bfr[j], acc[i][j], 0, 0, 0);
    }
    __syncthreads();
  }

  // C/D layout (m89): col = lane&15, row = quad*4 + reg
  if constexpr (EPI == 2) {
#pragma unroll
    for (int i = 0; i < 4; i++)
#pragma unroll
      for (int rg = 0; rg < 4; rg++) {
        const int r = m0 + wm + i * 16 + quad * 4 + rg;
        bool uu = true;
        if (pv0 != nullptr) {
          const float dE = -pv0[r] + 2.f * pv1[r];
          uu = rng_u01(usalt, (unsigned)r) < sigm(dE);
        }
        float sn = 0.f, sf = 0.f;
#pragma unroll
        for (int j = 0; j < 4; j++) {
          const int n = n0 + wn + j * 16 + lr;
          const float vw = acc[i][j][rg];
          const float cm = bf2f(mod[(size_t)r * 1024 + n]);
          const float s1 = softplus_(vw + cm);
          const float s2 = softplus_(wcs[n] - vw + cm);
          sn += uu ? s1 : s2;
          sf += uu ? s2 : s1;
        }
#pragma unroll
        for (int msk = 1; msk < 16; msk <<= 1) {
          sn += __shfl_xor(sn, msk, 64);
          sf += __shfl_xor(sf, msk, 64);
        }
        if (lr == 0) { atomicAdd(&p0[r], sn); atomicAdd(&p1[r], sf); }
      }
    return;
  }

  if constexpr (EPI == 1) {  // z-sums with v from OLD s; u_t computed inline
#pragma unroll
    for (int i = 0; i < 4; i++)
#pragma unroll
      for (int rg = 0; rg < 4; rg++) {
        const int r = m0 + wm + i * 16 + quad * 4 + rg;
        const float dE = -pv0[r] + 2.f * pv1[r];
        const bool uu = rng_u01(usalt, (unsigned)r) < sigm(dE);
        float q0 = 0.f, q1 = 0.f;
#pragma unroll
        for (int j = 0; j < 4; j++) {
          const int n = n0 + wn + j * 16 + lr;
          const float z = acc[i][j][rg];
          const float so = (sh[(size_t)r * LDA + n] != 0) ? 1.f : 0.f;
          const float v = uu ? so : 1.f - so;
          q0 += z; q1 += v * z;
        }
#pragma unroll
        for (int msk = 1; msk < 16; msk <<= 1) {
          q0 += __shfl_xor(q0, msk, 64);
          q1 += __shfl_xor(q1, msk, 64);
        }
        if (lr == 0) { atomicAdd(&p0[r], q0); atomicAdd(&p1[r], q1); }
      }
  }

  // sample + repack through LDS -> coalesced stores (EPI 0 and 1)
  const int myphase = wm >> 6;
#pragma unroll
  for (int ph = 0; ph < 2; ++ph) {
    if (myphase == ph) {
#pragma unroll
      for (int i = 0; i < 4; ++i)
#pragma unroll
        for (int rg = 0; rg < 4; ++rg) {
          const int rowl = i * 16 + quad * 4 + rg;
          const int r = m0 + wm + rowl;
#pragma unroll
          for (int jp = 0; jp < 2; ++jp) {
            const unsigned x =
                hash32((unsigned)(r << 10) + (unsigned)(n0 + wn + jp * 16 + lr), salt);
            const float flo = (float)(x & 0xFFFFu), fhi = (float)(x >> 16);
            sm[rowl * SLS + wn + jp * 16 + lr] = bern16(acc[i][jp][rg], flo);
            sm[rowl * SLS + wn + (jp + 2) * 16 + lr] = bern16(acc[i][jp + 2][rg], fhi);
          }
        }
    }
    __syncthreads();
#pragma unroll
    for (int p = 0; p < 4; ++p) {  // 64 rows x 256 B, fully coalesced
      const int c = p * 256 + t, rowl = c >> 4, chk = c & 15;
      const uint4 vv = *(const uint4*)((const char*)sm + rowl * (SLS * 2) + chk * 16);
      *(uint4*)(sh + (size_t)(m0 + ph * 64 + rowl) * LDA + n0 + chk * 8) = vv;
    }
    __syncthreads();
  }
}

// ------------------------- setup / small kernels ---------------------------
__global__ __launch_bounds__(256) void k_x(const float* __restrict__ cond,
                                           const float* __restrict__ fc1w,
                                           const float* __restrict__ fc1b, float* __restrict__ X) {
  int idx = blockIdx.x * 256 + threadIdx.x;
  int r = idx >> 6, k = idx & 63;
  X[idx] = tanhf(cond[r] * fc1w[k] + fc1b[k]);
}

__global__ __launch_bounds__(256) void k_g(const float* __restrict__ fc2w,
                                           const float* __restrict__ fc2b,
                                           const float* __restrict__ b, const float* __restrict__ c,
                                           float* __restrict__ Gb, float* __restrict__ Gc,
                                           float* __restrict__ cstb, float* __restrict__ cstc) {
  int idx = blockIdx.x * 256 + threadIdx.x;
  int j = idx >> 6, k = idx & 63;
  Gb[idx] = fc2w[(size_t)j * 64 + k] * b[j] + fc2w[(size_t)(1024 + j) * 64 + k];
  Gc[idx] = fc2w[(size_t)(2048 + j) * 64 + k] * c[j] + fc2w[(size_t)(3072 + j) * 64 + k];
  if (k == 0) {
    cstb[j] = b[j] + fc2b[j] * b[j] + fc2b[1024 + j];
    cstc[j] = c[j] + fc2b[2048 + j] * c[j] + fc2b[3072 + j];
  }
}

__global__ __launch_bounds__(256) void k_prep(const float* __restrict__ W,
                                              const float* __restrict__ Gb,
                                              const float* __restrict__ Gc,
                                              const float* __restrict__ cstb,
                                              const float* __restrict__ cstc,
                                              unsigned short* __restrict__ Wt,
                                              unsigned short* __restrict__ Wb) {
  int k = blockIdx.x * 256 + threadIdx.x;
  int n = blockIdx.y;
  if (k >= LDA) return;
  unsigned short wt, wb;
  if (k < 1024) {
    wt = f2bf(W[(size_t)k * 1024 + n]);
    wb = f2bf(W[(size_t)n * 1024 + k]);
  } else if (k < 1088) {
    int j = k - 1024;
    wt = f2bf(Gc[(size_t)n * 64 + j]);
    wb = f2bf(Gb[(size_t)n * 64 + j]);
  } else if (k == 1088) {
    wt = f2bf(cstc[n]);
    wb = f2bf(cstb[n]);
  } else { wt = 0; wb = 0; }
  Wt[(size_t)n * LDA + k] = wt;
  Wb[(size_t)n * LDA + k] = wb;
}

__global__ __launch_bounds__(256) void k_wcs(const float* __restrict__ W, float* __restrict__ wcs) {
  int n = blockIdx.x * 256 + threadIdx.x;
  float s = 0.f;
  for (int i = 0; i < 1024; i++) s += W[(size_t)i * 1024 + n];
  wcs[n] = s;
}

// out[128 x 128] = X @ G^T + cst, stored bf16
__global__ __launch_bounds__(256) void k_bmod(const float* __restrict__ X,
                                              const float* __restrict__ G,
                                              const float* __restrict__ cst,
                                              unsigned short* __restrict__ out) {
  __shared__ __align__(16) float Xs[128 * 64];
  __shared__ __align__(16) float Gs[128 * 64];
  const int t = threadIdx.x;
  const int r0 = blockIdx.x * 128, c0 = blockIdx.y * 128;
#pragma unroll
  for (int c = 0; c < 8; ++c) {
    int i4 = c * 256 + t;
    ((float4*)Xs)[i4] = ((const float4*)(X + (size_t)r0 * 64))[i4];
    ((float4*)Gs)[i4] = ((const float4*)(G + (size_t)c0 * 64))[i4];
  }
  __syncthreads();
  const int tr = (t >> 4) * 8, tc = (t & 15) * 8;
  float acc[8][8] = {};
  for (int k = 0; k < 64; k += 4) {
    float4 xa[8], gb[8];
#pragma unroll
    for (int i = 0; i < 8; i++) xa[i] = *(const float4*)(Xs + (tr + i) * 64 + k);
#pragma unroll
    for (int j = 0; j < 8; j++) gb[j] = *(const float4*)(Gs + (tc + j) * 64 + k);
#pragma unroll
    for (int i = 0; i < 8; i++)
#pragma unroll
      for (int j = 0; j < 8; j++)
        acc[i][j] += xa[i].x * gb[j].x + xa[i].y * gb[j].y + xa[i].z * gb[j].z + xa[i].w * gb[j].w;
  }
#pragma unroll
  for (int i = 0; i < 8; i++)
#pragma unroll
    for (int j = 0; j < 8; j++)
      out[(size_t)(r0 + tr + i) * 1024 + (c0 + tc + j)] = f2bf(acc[i][j] + cst[c0 + tc + j]);
}

__global__ __launch_bounds__(256) void k_sinit(const float* __restrict__ vdata,
                                               const float* __restrict__ X,
                                               unsigned short* __restrict__ S,
                                               unsigned short* __restrict__ H,
                                               unsigned short* __restrict__ V) {
  int k = blockIdx.x * 256 + threadIdx.x;
  int r = blockIdx.y;
  if (k >= LDA) return;
  const size_t o = (size_t)r * LDA + k;
  if (k < 1024) {
    float vd = vdata[(size_t)r * 1024 + k];
    V[o] = (vd != 0.f) ? (unsigned short)0x3F80 : (unsigned short)0;
    const bool u0 = rng_u01(USALT, (unsigned)r) < 0.5f;  // == EPI1 step-0 formula
    float sv = u0 ? vd : 1.f - vd;
    S[o] = (sv != 0.f) ? (unsigned short)0x3F80 : (unsigned short)0;
  } else {
    unsigned short xv;
    if (k < 1088) xv = f2bf(X[(size_t)r * 64 + (k - 1024)]);
    else if (k == 1088) xv = (unsigned short)0x3F80;
    else xv = 0;
    S[o] = xv; H[o] = xv;
  }
}

__global__ __launch_bounds__(256) void k_final(
    const unsigned short* __restrict__ V, const unsigned short* __restrict__ S,
    const unsigned short* __restrict__ bmod,
    const float* __restrict__ pv0, const float* __restrict__ pv1, unsigned usalt,
    const float* __restrict__ spn_d, const float* __restrict__ spf_d,
    const float* __restrict__ spn_m, const float* __restrict__ spf_m, float* __restrict__ fdiff) {
  __shared__ float red0[4], red1[4], red2[4];
  int r = blockIdx.x, t = threadIdx.x;
  const unsigned short* brow = bmod + (size_t)r * 1024;
  const unsigned short* vrow = V + (size_t)r * LDA;
  const unsigned short* srow = S + (size_t)r * LDA;
  float d0 = 0.f, d1 = 0.f, d2 = 0.f;
  for (int j = t; j < 1024; j += 256) {
    float bm = bf2f(brow[j]);
    d0 += bm;
    d1 += (vrow[j] != 0) ? bm : 0.f;
    d2 += (srow[j] != 0) ? bm : 0.f;
  }
  for (int m = 32; m >= 1; m >>= 1) {
    d0 += __shfl_xor(d0, m, 64);
    d1 += __shfl_xor(d1, m, 64);
    d2 += __shfl_xor(d2, m, 64);
  }
  if ((t & 63) == 0) { red0[t >> 6] = d0; red1[t >> 6] = d1; red2[t >> 6] = d2; }
  __syncthreads();
  if (t == 0) {
    d0 = red0[0] + red0[1] + red0[2] + red0[3];
    d1 = red1[0] + red1[1] + red1[2] + red1[3];
    d2 = red2[0] + red2[1] + red2[2] + red2[3];
    const float dE = -pv0[r] + 2.f * pv1[r];
    const bool uu = rng_u01(usalt, (unsigned)r) < sigm(dE);
    float Fn_d = -d1 - spn_d[r];
    float Ff_d = -(d0 - d1) - spf_d[r];
    float F_d = -lse2(-Fn_d, -Ff_d);
    float vbn = uu ? d2 : (d0 - d2);
    float Fn_m = -vbn - spn_m[r];
    float Ff_m = -(d0 - vbn) - spf_m[r];
    float F_m = -lse2(-Fn_m, -Ff_m);
    fdiff[r] = F_d - F_m;
  }
}

__global__ __launch_bounds__(256) void k_reduce(const float* __restrict__ fdiff,
                                                float* __restrict__ out) {
  __shared__ float red[4];
  int t = threadIdx.x;
  float s = 0.f;
  for (int i = t; i < NB; i += 256) s += fdiff[i];
  for (int m = 32; m >= 1; m >>= 1) s += __shfl_xor(s, m, 64);
  if ((t & 63) == 0) red[t >> 6] = s;
  __syncthreads();
  if (t == 0) out[0] = (red[0] + red[1] + red[2] + red[3]) * (1.0f / (float)NB);
}

// ---------------------------------------------------------------------------
extern "C" void kernel_launch(void* const* d_in, const int* in_sizes, int n_in, void* d_out,
                              int out_size, void* d_ws, size_t ws_size, hipStream_t stream) {
  const float* vdata = (const float*)d_in[0];
  const float* cond = (const float*)d_in[1];
  const float* W = (const float*)d_in[2];
  const float* bb = (const float*)d_in[3];
  const float* cc = (const float*)d_in[4];
  const float* fc1w = (const float*)d_in[5];
  const float* fc1b = (const float*)d_in[6];
  const float* fc2w = (const float*)d_in[7];
  const float* fc2b = (const float*)d_in[8];
  float* out = (float*)d_out;

  char* wp = (char*)d_ws;
  auto alloc = [&](size_t bytes) {
    char* p = wp;
    wp += (bytes + 255) & ~(size_t)255;
    return p;
  };
  unsigned short* Wt = (unsigned short*)alloc((size_t)1024 * LDA * 2);
  unsigned short* Wb = (unsigned short*)alloc((size_t)1024 * LDA * 2);
  float* wcs = (float*)alloc(1024 * 4);
  float* X = (float*)alloc((size_t)NB * 64 * 4);
  float* Gb = (float*)alloc((size_t)1024 * 64 * 4);
  float* Gc = (float*)alloc((size_t)1024 * 64 * 4);
  float* cstb = (float*)alloc(1024 * 4);
  float* cstc = (float*)alloc(1024 * 4);
  unsigned short* bmod = (unsigned short*)alloc((size_t)NB * 1024 * 2);
  unsigned short* cmod = (unsigned short*)alloc((size_t)NB * 1024 * 2);
  unsigned short* S = (unsigned short*)alloc((size_t)NB * LDA * 2);
  unsigned short* H = (unsigned short*)alloc((size_t)NB * LDA * 2);
  unsigned short* V = (unsigned short*)alloc((size_t)NB * LDA * 2);
  // per-step dE accumulators: pair t stored at pall + (t+1)*2*NB, t = -1..9
  float* pall = (float*)alloc((size_t)(KSTEPS + 1) * 2 * NB * 4);
  float* spn_d = (float*)alloc(NB * 4);  // contiguous with spf_d/spn_m/spf_m
  float* spf_d = (float*)alloc(NB * 4);
  float* spn_m = (float*)alloc(NB * 4);
  float* spf_m = (float*)alloc(NB * 4);
  float* fdiff = (float*)alloc(NB * 4);
  auto P0 = [&](int t) { return pall + (size_t)(t + 1) * 2 * NB; };
  auto P1 = [&](int t) { return pall + (size_t)(t + 1) * 2 * NB + NB; };

  hipMemsetAsync(pall, 0, (size_t)(KSTEPS + 1) * 2 * NB * 4 + (size_t)4 * NB * 4, stream);

  k_x<<<NB * 64 / 256, 256, 0, stream>>>(cond, fc1w, fc1b, X);
  k_g<<<1024 * 64 / 256, 256, 0, stream>>>(fc2w, fc2b, bb, cc, Gb, Gc, cstb, cstc);
  k_prep<<<dim3(5, 1024), 256, 0, stream>>>(W, Gb, Gc, cstb, cstc, Wt, Wb);
  k_wcs<<<4, 256, 0, stream>>>(W, wcs);
  dim3 bgrid(NB / 128, 1024 / 128);
  k_bmod<<<bgrid, 256, 0, stream>>>(X, Gb, cstb, bmod);
  k_bmod<<<bgrid, 256, 0, stream>>>(X, Gc, cstc, cmod);
  k_sinit<<<dim3(5, NB), 256, 0, stream>>>(vdata, X, S, H, V);

  for (int step = 0; step < KSTEPS; ++step) {
    // z1 = sW + c_mod (ext-K); h ~ Bern(sigm(z1)) -> H
    gemm_bt<0><<<1024, 256, 0, stream>>>(S, Wt, H, nullptr, nullptr, nullptr, nullptr, 0u,
                                         nullptr, nullptr, 2000u + (unsigned)step, LDA);
    // z2 = hW^T + b_mod (ext-K); u_t inline from step-1 sums; dE partials -> step t;
    // s_new ~ Bern(sigm(z2)) -> S
    gemm_bt<1><<<1024, 256, 0, stream>>>(H, Wb, S, nullptr, nullptr, P0(step - 1), P1(step - 1),
                                         USALT + (unsigned)step, P0(step), P1(step),
                                         3000u + (unsigned)step, LDA);
  }

  // Free-energy softplus sums (K=1024 plain vW + cmod read). Data pass u=1; model
  // pass computes u_K inline from step K-1 sums.
  gemm_bt<2><<<1024, 256, 0, stream>>>(V, Wt, nullptr, cmod, wcs, nullptr, nullptr, 0u,
                                       spn_d, spf_d, 0u, 1024);
  gemm_bt<2><<<1024, 256, 0, stream>>>(S, Wt, nullptr, cmod, wcs, P0(KSTEPS - 1), P1(KSTEPS - 1),
                                       USALT + KSTEPS, spn_m, spf_m, 0u, 1024);
  k_final<<<NB, 256, 0, stream>>>(V, S, bmod, P0(KSTEPS - 1), P1(KSTEPS - 1), USALT + KSTEPS,
                                  spn_d, spf_d, spn_m, spf_m, fdiff);
  k_reduce<<<1, 256, 0, stream>>>(fdiff, out);
}